// Round 2
// baseline (1060.886 us; speedup 1.0000x reference)
//
#include <hip/hip_runtime.h>

// GAT 2-layer, f32. N=50000 nodes, E=1.6M edges, L1: 256->8x32, L2: 256->2.
// Structure: device-built CSR (hist/scan/scatter) -> per-dst-block aggregation,
// no float atomics. Softmax max-subtraction skipped (shift-invariant, |e| small).

#define NN 50000
#define NE 1600000
#define GR 32  // rows per gemm1 block

__global__ __launch_bounds__(256) void k_hist(const int* __restrict__ dst,
                                              int* __restrict__ counts, int E) {
  for (int i = blockIdx.x * blockDim.x + threadIdx.x; i < E;
       i += gridDim.x * blockDim.x)
    atomicAdd(&counts[dst[i]], 1);
}

__global__ __launch_bounds__(1024) void k_scan(const int* __restrict__ counts,
                                               int* __restrict__ offs,
                                               int* __restrict__ cursor, int n) {
  __shared__ int buf[1024];
  __shared__ int carry;
  int tid = threadIdx.x;
  if (tid == 0) carry = 0;
  __syncthreads();
  int nChunks = (n + 1023) / 1024;
  for (int c = 0; c < nChunks; ++c) {
    int i = c * 1024 + tid;
    int v = (i < n) ? counts[i] : 0;
    buf[tid] = v;
    __syncthreads();
    for (int off = 1; off < 1024; off <<= 1) {
      int t = (tid >= off) ? buf[tid - off] : 0;
      __syncthreads();
      buf[tid] += t;
      __syncthreads();
    }
    int excl = carry + buf[tid] - v;
    if (i < n) { offs[i] = excl; cursor[i] = excl; }
    __syncthreads();
    if (tid == 1023) carry += buf[1023];
    __syncthreads();
  }
  if (tid == 0) offs[n] = carry;
}

__global__ __launch_bounds__(256) void k_scatter(const int* __restrict__ dst,
                                                 int* __restrict__ cursor,
                                                 int* __restrict__ perm, int E) {
  for (int i = blockIdx.x * blockDim.x + threadIdx.x; i < E;
       i += gridDim.x * blockDim.x) {
    int p = atomicAdd(&cursor[dst[i]], 1);
    perm[p] = i;
  }
}

// feat1 = x @ W1 (256x256), fused el/er head reductions.
__global__ __launch_bounds__(256) void k_gemm1(
    const float* __restrict__ x, const float* __restrict__ W,
    const float* __restrict__ al, const float* __restrict__ ar,
    float* __restrict__ feat, float* __restrict__ el, float* __restrict__ er,
    int n) {
  __shared__ float xs[GR][256];
  int row0 = blockIdx.x * GR;
  int j = threadIdx.x;
  for (int idx = threadIdx.x; idx < GR * 256; idx += 256) {
    int r = idx >> 8, k = idx & 255;
    int row = row0 + r;
    xs[r][k] = (row < n) ? x[row * 256 + k] : 0.f;
  }
  __syncthreads();
  float acc[GR];
#pragma unroll
  for (int r = 0; r < GR; r++) acc[r] = 0.f;
  for (int k = 0; k < 256; k += 4) {
    float w0 = W[(k + 0) * 256 + j];
    float w1 = W[(k + 1) * 256 + j];
    float w2 = W[(k + 2) * 256 + j];
    float w3 = W[(k + 3) * 256 + j];
#pragma unroll
    for (int r = 0; r < GR; r++) {
      float4 xv = *reinterpret_cast<const float4*>(&xs[r][k]);
      acc[r] = fmaf(xv.x, w0,
               fmaf(xv.y, w1, fmaf(xv.z, w2, fmaf(xv.w, w3, acc[r]))));
    }
  }
  float alv = al[j], arv = ar[j];
  int hh = j >> 5;
  for (int r = 0; r < GR; r++) {
    int row = row0 + r;
    if (row >= n) break;
    feat[row * 256 + j] = acc[r];
    float pl = acc[r] * alv, pr = acc[r] * arv;
#pragma unroll
    for (int off = 16; off; off >>= 1) {
      pl += __shfl_xor(pl, off, 32);
      pr += __shfl_xor(pr, off, 32);
    }
    if ((j & 31) == 0) {
      el[row * 8 + hh] = pl;
      er[row * 8 + hh] = pr;
    }
  }
}

// One block per dst node: out[dst,j] = (sum_e ee*feat[src_e,j]) / sum_e ee
// fused +b1 and ELU. ee = exp(leaky_relu(el[src]+er[dst])).
__global__ __launch_bounds__(256) void k_agg1(
    const float* __restrict__ feat, const float* __restrict__ el,
    const float* __restrict__ er, const int* __restrict__ offs,
    const int* __restrict__ perm, const int* __restrict__ src,
    const float* __restrict__ b1, float* __restrict__ hout, int n) {
  int dn = blockIdx.x;
  if (dn >= n) return;
  int j = threadIdx.x;
  int hh = j >> 5;
  float erd = er[dn * 8 + hh];
  int beg = offs[dn], end = offs[dn + 1];
  float acc = 0.f, den = 0.f;
  for (int e = beg; e < end; ++e) {
    int s = src[perm[e]];
    float ev = el[s * 8 + hh] + erd;
    ev = ev >= 0.f ? ev : 0.2f * ev;
    float ee = __expf(ev);
    den += ee;
    acc = fmaf(ee, feat[s * 256 + j], acc);
  }
  float v = acc / fmaxf(den, 1e-16f) + b1[j];
  hout[dn * 256 + j] = v > 0.f ? v : expm1f(v);
}

// feat2 = h @ W2 (256x2), one wave per node, fused el2/er2.
__global__ __launch_bounds__(256) void k_gemm2(
    const float* __restrict__ h, const float* __restrict__ W2,
    const float* __restrict__ al2, const float* __restrict__ ar2,
    float* __restrict__ feat2, float* __restrict__ el2, float* __restrict__ er2,
    int n) {
  __shared__ float w2s[512];
  for (int i = threadIdx.x; i < 512; i += 256) w2s[i] = W2[i];
  __syncthreads();
  int wave = threadIdx.x >> 6, lane = threadIdx.x & 63;
  int node = blockIdx.x * 4 + wave;
  if (node >= n) return;
  const float* hr = h + (size_t)node * 256;
  float4 hv = *reinterpret_cast<const float4*>(&hr[lane * 4]);
  float a0 = 0.f, a1 = 0.f;
  int kb = lane * 4;
  a0 = fmaf(hv.x, w2s[(kb + 0) * 2 + 0], a0);
  a1 = fmaf(hv.x, w2s[(kb + 0) * 2 + 1], a1);
  a0 = fmaf(hv.y, w2s[(kb + 1) * 2 + 0], a0);
  a1 = fmaf(hv.y, w2s[(kb + 1) * 2 + 1], a1);
  a0 = fmaf(hv.z, w2s[(kb + 2) * 2 + 0], a0);
  a1 = fmaf(hv.z, w2s[(kb + 2) * 2 + 1], a1);
  a0 = fmaf(hv.w, w2s[(kb + 3) * 2 + 0], a0);
  a1 = fmaf(hv.w, w2s[(kb + 3) * 2 + 1], a1);
#pragma unroll
  for (int off = 32; off; off >>= 1) {
    a0 += __shfl_xor(a0, off, 64);
    a1 += __shfl_xor(a1, off, 64);
  }
  if (lane == 0) {
    feat2[node * 2 + 0] = a0;
    feat2[node * 2 + 1] = a1;
    el2[node] = a0 * al2[0] + a1 * al2[1];
    er2[node] = a0 * ar2[0] + a1 * ar2[1];
  }
}

// One thread per dst node; fused +b2 and log_softmax over 2 classes.
__global__ __launch_bounds__(256) void k_agg2(
    const float* __restrict__ feat2, const float* __restrict__ el2,
    const float* __restrict__ er2, const int* __restrict__ offs,
    const int* __restrict__ perm, const int* __restrict__ src,
    const float* __restrict__ b2, float* __restrict__ out, int n) {
  int dn = blockIdx.x * blockDim.x + threadIdx.x;
  if (dn >= n) return;
  float erd = er2[dn];
  int beg = offs[dn], end = offs[dn + 1];
  float den = 0.f, a0 = 0.f, a1 = 0.f;
  for (int e = beg; e < end; ++e) {
    int s = src[perm[e]];
    float ev = el2[s] + erd;
    ev = ev >= 0.f ? ev : 0.2f * ev;
    float ee = __expf(ev);
    den += ee;
    a0 = fmaf(ee, feat2[s * 2 + 0], a0);
    a1 = fmaf(ee, feat2[s * 2 + 1], a1);
  }
  float inv = 1.f / fmaxf(den, 1e-16f);
  float z0 = a0 * inv + b2[0];
  float z1 = a1 * inv + b2[1];
  float m = fmaxf(z0, z1);
  float lse = m + logf(__expf(z0 - m) + __expf(z1 - m));
  out[dn * 2 + 0] = z0 - lse;
  out[dn * 2 + 1] = z1 - lse;
}

extern "C" void kernel_launch(void* const* d_in, const int* in_sizes, int n_in,
                              void* d_out, int out_size, void* d_ws,
                              size_t ws_size, hipStream_t stream) {
  const float* x   = (const float*)d_in[0];
  const int* esrc  = (const int*)d_in[1];
  const int* edst  = (const int*)d_in[2];
  const float* W1  = (const float*)d_in[3];
  const float* al1 = (const float*)d_in[4];
  const float* ar1 = (const float*)d_in[5];
  const float* b1  = (const float*)d_in[6];
  const float* W2  = (const float*)d_in[7];
  const float* al2 = (const float*)d_in[8];
  const float* ar2 = (const float*)d_in[9];
  const float* b2  = (const float*)d_in[10];
  float* out = (float*)d_out;

  size_t off = 0;
  auto alloc = [&](size_t bytes) {
    void* p = (char*)d_ws + off;
    off += (bytes + 255) & ~(size_t)255;
    return p;
  };
  float* feat1 = (float*)alloc((size_t)NN * 256 * 4);
  float* hbuf  = (float*)alloc((size_t)NN * 256 * 4);
  float* el1   = (float*)alloc((size_t)NN * 8 * 4);
  float* er1   = (float*)alloc((size_t)NN * 8 * 4);
  float* feat2 = (float*)alloc((size_t)NN * 2 * 4);
  float* el2   = (float*)alloc((size_t)NN * 4);
  float* er2   = (float*)alloc((size_t)NN * 4);
  int* counts  = (int*)alloc((size_t)NN * 4);
  int* offs    = (int*)alloc((size_t)(NN + 1) * 4);
  int* cursor  = (int*)alloc((size_t)NN * 4);
  int* perm    = (int*)alloc((size_t)NE * 4);

  hipMemsetAsync(counts, 0, (size_t)NN * 4, stream);
  k_hist<<<2048, 256, 0, stream>>>(edst, counts, NE);
  k_scan<<<1, 1024, 0, stream>>>(counts, offs, cursor, NN);
  k_scatter<<<2048, 256, 0, stream>>>(edst, cursor, perm, NE);

  k_gemm1<<<(NN + GR - 1) / GR, 256, 0, stream>>>(x, W1, al1, ar1, feat1, el1,
                                                  er1, NN);
  k_agg1<<<NN, 256, 0, stream>>>(feat1, el1, er1, offs, perm, esrc, b1, hbuf,
                                 NN);
  k_gemm2<<<(NN + 3) / 4, 256, 0, stream>>>(hbuf, W2, al2, ar2, feat2, el2,
                                            er2, NN);
  k_agg2<<<(NN + 255) / 256, 256, 0, stream>>>(feat2, el2, er2, offs, perm,
                                               esrc, b2, out, NN);
}

// Round 4
// 645.211 us; speedup vs baseline: 1.6442x; 1.6442x over previous
//
#include <hip/hip_runtime.h>

// GAT 2-layer, f32. N=50000, E=1.6M. L1: 256->8x32, L2: 256->2.
// CSR by dst stores SRC NODE IDS directly (no edge-id indirection).
// agg1: block-per-dst, wave-per-edge, float4 lanes, LDS-staged indices.

#define NN 50000
#define NE 1600000
#define GR 32   // rows per gemm1 block
#define CH 256  // edge chunk staged in LDS (agg1)

__global__ __launch_bounds__(256) void k_hist(const int* __restrict__ dst,
                                              int* __restrict__ counts, int E) {
  for (int i = blockIdx.x * blockDim.x + threadIdx.x; i < E;
       i += gridDim.x * blockDim.x)
    atomicAdd(&counts[dst[i]], 1);
}

// scan stage 1: per-block (256) exclusive scan, block totals.
__global__ __launch_bounds__(256) void k_scan1(const int* __restrict__ counts,
                                               int* __restrict__ offs,
                                               int* __restrict__ btot, int n) {
  __shared__ int buf[256];
  int tid = threadIdx.x;
  int i = blockIdx.x * 256 + tid;
  int v = (i < n) ? counts[i] : 0;
  buf[tid] = v;
  __syncthreads();
  for (int off = 1; off < 256; off <<= 1) {
    int t = (tid >= off) ? buf[tid - off] : 0;
    __syncthreads();
    buf[tid] += t;
    __syncthreads();
  }
  if (i < n) offs[i] = buf[tid] - v;
  if (tid == 255) btot[blockIdx.x] = buf[255];
}

// scan stage 2: scan block totals (nb <= 256), write grand total to offs[n].
__global__ __launch_bounds__(256) void k_scan2(int* __restrict__ btot,
                                               int* __restrict__ bofs,
                                               int* __restrict__ offs, int nb,
                                               int n) {
  __shared__ int buf[256];
  int tid = threadIdx.x;
  int v = (tid < nb) ? btot[tid] : 0;
  buf[tid] = v;
  __syncthreads();
  for (int off = 1; off < 256; off <<= 1) {
    int t = (tid >= off) ? buf[tid - off] : 0;
    __syncthreads();
    buf[tid] += t;
    __syncthreads();
  }
  if (tid < nb) bofs[tid] = buf[tid] - v;
  if (tid == 255) offs[n] = buf[255];
}

// scan stage 3: add block offsets, init cursor.
__global__ __launch_bounds__(256) void k_scan3(int* __restrict__ offs,
                                               const int* __restrict__ bofs,
                                               int* __restrict__ cursor, int n) {
  int i = blockIdx.x * 256 + threadIdx.x;
  if (i < n) {
    int v = offs[i] + bofs[blockIdx.x];
    offs[i] = v;
    cursor[i] = v;
  }
}

// scatter: csr[slot] = src node id (fused indirection).
__global__ __launch_bounds__(256) void k_scatter(const int* __restrict__ dst,
                                                 const int* __restrict__ src,
                                                 int* __restrict__ cursor,
                                                 int* __restrict__ csr, int E) {
  for (int i = blockIdx.x * blockDim.x + threadIdx.x; i < E;
       i += gridDim.x * blockDim.x) {
    int p = atomicAdd(&cursor[dst[i]], 1);
    csr[p] = src[i];
  }
}

// feat1 = x @ W1 (256x256), fused el/er head reductions.
__global__ __launch_bounds__(256) void k_gemm1(
    const float* __restrict__ x, const float* __restrict__ W,
    const float* __restrict__ al, const float* __restrict__ ar,
    float* __restrict__ feat, float* __restrict__ el, float* __restrict__ er,
    int n) {
  __shared__ float xs[GR][256];
  int row0 = blockIdx.x * GR;
  int j = threadIdx.x;
  for (int idx = threadIdx.x; idx < GR * 256; idx += 256) {
    int r = idx >> 8, k = idx & 255;
    int row = row0 + r;
    xs[r][k] = (row < n) ? x[row * 256 + k] : 0.f;
  }
  __syncthreads();
  float acc[GR];
#pragma unroll
  for (int r = 0; r < GR; r++) acc[r] = 0.f;
  for (int k = 0; k < 256; k += 4) {
    float w0 = W[(k + 0) * 256 + j];
    float w1 = W[(k + 1) * 256 + j];
    float w2 = W[(k + 2) * 256 + j];
    float w3 = W[(k + 3) * 256 + j];
#pragma unroll
    for (int r = 0; r < GR; r++) {
      float4 xv = *reinterpret_cast<const float4*>(&xs[r][k]);
      acc[r] = fmaf(xv.x, w0,
               fmaf(xv.y, w1, fmaf(xv.z, w2, fmaf(xv.w, w3, acc[r]))));
    }
  }
  float alv = al[j], arv = ar[j];
  int hh = j >> 5;
  for (int r = 0; r < GR; r++) {
    int row = row0 + r;
    if (row >= n) break;
    feat[row * 256 + j] = acc[r];
    float pl = acc[r] * alv, pr = acc[r] * arv;
#pragma unroll
    for (int off = 16; off; off >>= 1) {
      pl += __shfl_xor(pl, off, 32);
      pr += __shfl_xor(pr, off, 32);
    }
    if ((j & 31) == 0) {
      el[row * 8 + hh] = pl;
      er[row * 8 + hh] = pr;
    }
  }
}

// Block per dst node. 4 waves process 4 edges concurrently; each lane holds
// float4 of the 256-wide row. Per-head denominators. LDS combine at end.
__global__ __launch_bounds__(256) void k_agg1(
    const float* __restrict__ feat, const float* __restrict__ el,
    const float* __restrict__ er, const int* __restrict__ offs,
    const int* __restrict__ csr, const float* __restrict__ b1,
    float* __restrict__ hout, int n) {
  __shared__ int s_idx[CH];
  __shared__ float psum[4][256];
  __shared__ float pden[4][8];
  int dn = blockIdx.x;
  int tid = threadIdx.x;
  int w = tid >> 6, l = tid & 63;
  int hh = l >> 3;  // head of this lane's 4 columns
  float erd = er[dn * 8 + hh];
  int beg = offs[dn], end = offs[dn + 1];
  float4 acc = {0.f, 0.f, 0.f, 0.f};
  float den = 0.f;
  for (int base = beg; base < end; base += CH) {
    int cnt = min(CH, end - base);
    __syncthreads();
    if (tid < cnt) s_idx[tid] = csr[base + tid];
    __syncthreads();
    for (int i = w; i < cnt; i += 4) {
      int s = s_idx[i];
      float ev = el[s * 8 + hh] + erd;
      ev = ev >= 0.f ? ev : 0.2f * ev;
      float ee = __expf(ev);
      den += ee;
      float4 fv = *reinterpret_cast<const float4*>(feat + (size_t)s * 256 + l * 4);
      acc.x = fmaf(ee, fv.x, acc.x);
      acc.y = fmaf(ee, fv.y, acc.y);
      acc.z = fmaf(ee, fv.z, acc.z);
      acc.w = fmaf(ee, fv.w, acc.w);
    }
  }
  *reinterpret_cast<float4*>(&psum[w][l * 4]) = acc;
  if ((l & 7) == 0) pden[w][hh] = den;
  __syncthreads();
  int j = tid;
  float num = psum[0][j] + psum[1][j] + psum[2][j] + psum[3][j];
  int jh = j >> 5;
  float d = pden[0][jh] + pden[1][jh] + pden[2][jh] + pden[3][jh];
  float v = num / fmaxf(d, 1e-16f) + b1[j];
  hout[dn * 256 + j] = v > 0.f ? v : expm1f(v);
}

// feat2 = h @ W2 (256x2), one wave per node, fused el2/er2.
__global__ __launch_bounds__(256) void k_gemm2(
    const float* __restrict__ h, const float* __restrict__ W2,
    const float* __restrict__ al2, const float* __restrict__ ar2,
    float* __restrict__ feat2, float* __restrict__ el2, float* __restrict__ er2,
    int n) {
  __shared__ float w2s[512];
  for (int i = threadIdx.x; i < 512; i += 256) w2s[i] = W2[i];
  __syncthreads();
  int wave = threadIdx.x >> 6, lane = threadIdx.x & 63;
  int node = blockIdx.x * 4 + wave;
  if (node >= n) return;
  const float* hr = h + (size_t)node * 256;
  float4 hv = *reinterpret_cast<const float4*>(&hr[lane * 4]);
  float a0 = 0.f, a1 = 0.f;
  int kb = lane * 4;
  a0 = fmaf(hv.x, w2s[(kb + 0) * 2 + 0], a0);
  a1 = fmaf(hv.x, w2s[(kb + 0) * 2 + 1], a1);
  a0 = fmaf(hv.y, w2s[(kb + 1) * 2 + 0], a0);
  a1 = fmaf(hv.y, w2s[(kb + 1) * 2 + 1], a1);
  a0 = fmaf(hv.z, w2s[(kb + 2) * 2 + 0], a0);
  a1 = fmaf(hv.z, w2s[(kb + 2) * 2 + 1], a1);
  a0 = fmaf(hv.w, w2s[(kb + 3) * 2 + 0], a0);
  a1 = fmaf(hv.w, w2s[(kb + 3) * 2 + 1], a1);
#pragma unroll
  for (int off = 32; off; off >>= 1) {
    a0 += __shfl_xor(a0, off, 64);
    a1 += __shfl_xor(a1, off, 64);
  }
  if (lane == 0) {
    feat2[node * 2 + 0] = a0;
    feat2[node * 2 + 1] = a1;
    el2[node] = a0 * al2[0] + a1 * al2[1];
    er2[node] = a0 * ar2[0] + a1 * ar2[1];
  }
}

// Wave per dst node; lanes = edges; shuffle reduce; fused log_softmax.
__global__ __launch_bounds__(256) void k_agg2(
    const float* __restrict__ feat2, const float* __restrict__ el2,
    const float* __restrict__ er2, const int* __restrict__ offs,
    const int* __restrict__ csr, const float* __restrict__ b2,
    float* __restrict__ out, int n) {
  int dn = blockIdx.x * 4 + (threadIdx.x >> 6);
  int l = threadIdx.x & 63;
  if (dn >= n) return;
  float erd = er2[dn];
  int beg = offs[dn], end = offs[dn + 1];
  float den = 0.f, a0 = 0.f, a1 = 0.f;
  for (int e = beg + l; e < end; e += 64) {
    int s = csr[e];
    float ev = el2[s] + erd;
    ev = ev >= 0.f ? ev : 0.2f * ev;
    float ee = __expf(ev);
    den += ee;
    float2 f2 = *reinterpret_cast<const float2*>(feat2 + (size_t)s * 2);
    a0 = fmaf(ee, f2.x, a0);
    a1 = fmaf(ee, f2.y, a1);
  }
#pragma unroll
  for (int off = 32; off; off >>= 1) {
    den += __shfl_xor(den, off, 64);
    a0 += __shfl_xor(a0, off, 64);
    a1 += __shfl_xor(a1, off, 64);
  }
  if (l == 0) {
    float inv = 1.f / fmaxf(den, 1e-16f);
    float z0 = a0 * inv + b2[0];
    float z1 = a1 * inv + b2[1];
    float m = fmaxf(z0, z1);
    float lse = m + logf(__expf(z0 - m) + __expf(z1 - m));
    out[dn * 2 + 0] = z0 - lse;
    out[dn * 2 + 1] = z1 - lse;
  }
}

extern "C" void kernel_launch(void* const* d_in, const int* in_sizes, int n_in,
                              void* d_out, int out_size, void* d_ws,
                              size_t ws_size, hipStream_t stream) {
  const float* x   = (const float*)d_in[0];
  const int* esrc  = (const int*)d_in[1];
  const int* edst  = (const int*)d_in[2];
  const float* W1  = (const float*)d_in[3];
  const float* al1 = (const float*)d_in[4];
  const float* ar1 = (const float*)d_in[5];
  const float* b1  = (const float*)d_in[6];
  const float* W2  = (const float*)d_in[7];
  const float* al2 = (const float*)d_in[8];
  const float* ar2 = (const float*)d_in[9];
  const float* b2  = (const float*)d_in[10];
  float* out = (float*)d_out;

  size_t off = 0;
  auto alloc = [&](size_t bytes) {
    void* p = (char*)d_ws + off;
    off += (bytes + 255) & ~(size_t)255;
    return p;
  };
  float* feat1 = (float*)alloc((size_t)NN * 256 * 4);
  float* hbuf  = (float*)alloc((size_t)NN * 256 * 4);
  float* el1   = (float*)alloc((size_t)NN * 8 * 4);
  float* er1   = (float*)alloc((size_t)NN * 8 * 4);
  float* feat2 = (float*)alloc((size_t)NN * 2 * 4);
  float* el2   = (float*)alloc((size_t)NN * 4);
  float* er2   = (float*)alloc((size_t)NN * 4);
  int* counts  = (int*)alloc((size_t)NN * 4);
  int* offs    = (int*)alloc((size_t)(NN + 1) * 4);
  int* cursor  = (int*)alloc((size_t)NN * 4);
  int* csr     = (int*)alloc((size_t)NE * 4);
  int* btot    = (int*)alloc(256 * 4);
  int* bofs    = (int*)alloc(256 * 4);

  const int NB = (NN + 255) / 256;  // 196

  hipMemsetAsync(counts, 0, (size_t)NN * 4, stream);
  k_hist<<<2048, 256, 0, stream>>>(edst, counts, NE);
  k_scan1<<<NB, 256, 0, stream>>>(counts, offs, btot, NN);
  k_scan2<<<1, 256, 0, stream>>>(btot, bofs, offs, NB, NN);
  k_scan3<<<NB, 256, 0, stream>>>(offs, bofs, cursor, NN);
  k_scatter<<<2048, 256, 0, stream>>>(edst, esrc, cursor, csr, NE);

  k_gemm1<<<(NN + GR - 1) / GR, 256, 0, stream>>>(x, W1, al1, ar1, feat1, el1,
                                                  er1, NN);
  k_agg1<<<NN, 256, 0, stream>>>(feat1, el1, er1, offs, csr, b1, hbuf, NN);
  k_gemm2<<<(NN + 3) / 4, 256, 0, stream>>>(hbuf, W2, al2, ar2, feat2, el2,
                                            er2, NN);
  k_agg2<<<(NN + 3) / 4, 256, 0, stream>>>(feat2, el2, er2, offs, csr,
                                           b2, out, NN);
}

// Round 6
// 430.311 us; speedup vs baseline: 2.4654x; 1.4994x over previous
//
#include <hip/hip_runtime.h>

// GAT 2-layer. N=50000, E=1.6M. L1: 256->8x32 (bf16 MFMA), L2: 256->2.
// CSR by dst holds src ids. feat1/h stored bf16 to halve gather traffic.

#define NN 50000
#define NE 1600000
#define CH 256  // edge chunk staged in LDS (agg1)

typedef __attribute__((ext_vector_type(8))) short short8;
typedef __attribute__((ext_vector_type(4))) float f32x4;

__device__ inline unsigned short f2bf(float f) {
  unsigned int u = __float_as_uint(f);
  unsigned int r = (u + 0x7fffu + ((u >> 16) & 1u)) >> 16;
  return (unsigned short)r;
}
__device__ inline float bf2f(unsigned short h) {
  return __uint_as_float(((unsigned int)h) << 16);
}

__global__ __launch_bounds__(256) void k_hist(const int* __restrict__ dst,
                                              int* __restrict__ counts, int E) {
  for (int i = blockIdx.x * blockDim.x + threadIdx.x; i < E;
       i += gridDim.x * blockDim.x)
    atomicAdd(&counts[dst[i]], 1);
}

__global__ __launch_bounds__(256) void k_scan1(const int* __restrict__ counts,
                                               int* __restrict__ offs,
                                               int* __restrict__ btot, int n) {
  __shared__ int buf[256];
  int tid = threadIdx.x;
  int i = blockIdx.x * 256 + tid;
  int v = (i < n) ? counts[i] : 0;
  buf[tid] = v;
  __syncthreads();
  for (int off = 1; off < 256; off <<= 1) {
    int t = (tid >= off) ? buf[tid - off] : 0;
    __syncthreads();
    buf[tid] += t;
    __syncthreads();
  }
  if (i < n) offs[i] = buf[tid] - v;
  if (tid == 255) btot[blockIdx.x] = buf[255];
}

__global__ __launch_bounds__(256) void k_scan2(int* __restrict__ btot,
                                               int* __restrict__ bofs,
                                               int* __restrict__ offs, int nb,
                                               int n) {
  __shared__ int buf[256];
  int tid = threadIdx.x;
  int v = (tid < nb) ? btot[tid] : 0;
  buf[tid] = v;
  __syncthreads();
  for (int off = 1; off < 256; off <<= 1) {
    int t = (tid >= off) ? buf[tid - off] : 0;
    __syncthreads();
    buf[tid] += t;
    __syncthreads();
  }
  if (tid < nb) bofs[tid] = buf[tid] - v;
  if (tid == 255) offs[n] = buf[255];
}

__global__ __launch_bounds__(256) void k_scan3(int* __restrict__ offs,
                                               const int* __restrict__ bofs,
                                               int* __restrict__ cursor, int n) {
  int i = blockIdx.x * 256 + threadIdx.x;
  if (i < n) {
    int v = offs[i] + bofs[blockIdx.x];
    offs[i] = v;
    cursor[i] = v;
  }
}

__global__ __launch_bounds__(256) void k_scatter(const int* __restrict__ dst,
                                                 const int* __restrict__ src,
                                                 int* __restrict__ cursor,
                                                 int* __restrict__ csr, int E) {
  for (int i = blockIdx.x * blockDim.x + threadIdx.x; i < E;
       i += gridDim.x * blockDim.x) {
    int p = atomicAdd(&cursor[dst[i]], 1);
    csr[p] = src[i];
  }
}

// Pack W1 (256x256 f32 row-major [k][n]) into MFMA B-fragment order, bf16:
// W1p[((nf*8+ks)*64+lane)*8 + j] = bf16(W1[(ks*32+(lane>>4)*8+j)*256 + nf*16+(lane&15)])
__global__ __launch_bounds__(256) void k_packw(const float* __restrict__ W1,
                                               unsigned short* __restrict__ W1p) {
  int idx = blockIdx.x * 256 + threadIdx.x;  // 8192 total
  int nf = idx >> 9, rem = idx & 511;
  int ks = rem >> 6, lane = rem & 63;
  int n = nf * 16 + (lane & 15);
  int kb = ks * 32 + (lane >> 4) * 8;
#pragma unroll
  for (int j = 0; j < 8; ++j)
    W1p[(size_t)idx * 8 + j] = f2bf(W1[(kb + j) * 256 + n]);
}

// MFMA GEMM: feat_bf16 = bf16(x) @ bf16(W1). Wave handles 32 rows x 256 cols.
// A layout (16x16x32): lane l: row=l&15, k=(l>>4)*8+j. D: col=l&15, row=(l>>4)*4+q.
__global__ __launch_bounds__(256) void k_gemm1m(
    const float* __restrict__ x, const unsigned short* __restrict__ W1p,
    unsigned short* __restrict__ featb, int n) {
  int w = threadIdx.x >> 6, lane = threadIdx.x & 63;
  int tile = (blockIdx.x * 4 + w) * 32;
  if (tile >= n) return;
  int r0 = lane & 15, kgrp = lane >> 4;
  f32x4 acc[16][2];
#pragma unroll
  for (int nf = 0; nf < 16; ++nf)
#pragma unroll
    for (int mf = 0; mf < 2; ++mf) acc[nf][mf] = (f32x4){0.f, 0.f, 0.f, 0.f};

  for (int ks = 0; ks < 8; ++ks) {
    int kb = ks * 32 + kgrp * 8;
    short8 a0, a1;
    {
      int row = tile + r0;  // always < n given tile < n and 32-row tiles
      const float* p = x + (size_t)row * 256 + kb;
      float4 v0 = *reinterpret_cast<const float4*>(p);
      float4 v1 = *reinterpret_cast<const float4*>(p + 4);
      a0[0] = (short)f2bf(v0.x); a0[1] = (short)f2bf(v0.y);
      a0[2] = (short)f2bf(v0.z); a0[3] = (short)f2bf(v0.w);
      a0[4] = (short)f2bf(v1.x); a0[5] = (short)f2bf(v1.y);
      a0[6] = (short)f2bf(v1.z); a0[7] = (short)f2bf(v1.w);
    }
    {
      int row = tile + 16 + r0;
      if (row < n) {
        const float* p = x + (size_t)row * 256 + kb;
        float4 v0 = *reinterpret_cast<const float4*>(p);
        float4 v1 = *reinterpret_cast<const float4*>(p + 4);
        a1[0] = (short)f2bf(v0.x); a1[1] = (short)f2bf(v0.y);
        a1[2] = (short)f2bf(v0.z); a1[3] = (short)f2bf(v0.w);
        a1[4] = (short)f2bf(v1.x); a1[5] = (short)f2bf(v1.y);
        a1[6] = (short)f2bf(v1.z); a1[7] = (short)f2bf(v1.w);
      } else {
#pragma unroll
        for (int j = 0; j < 8; ++j) a1[j] = 0;
      }
    }
#pragma unroll
    for (int nf = 0; nf < 16; ++nf) {
      short8 b = *reinterpret_cast<const short8*>(
          W1p + ((size_t)(nf * 8 + ks) * 64 + lane) * 8);
      acc[nf][0] = __builtin_amdgcn_mfma_f32_16x16x32_bf16(a0, b, acc[nf][0], 0, 0, 0);
      acc[nf][1] = __builtin_amdgcn_mfma_f32_16x16x32_bf16(a1, b, acc[nf][1], 0, 0, 0);
    }
  }
#pragma unroll
  for (int nf = 0; nf < 16; ++nf)
#pragma unroll
    for (int mf = 0; mf < 2; ++mf)
#pragma unroll
      for (int q = 0; q < 4; ++q) {
        int row = tile + mf * 16 + kgrp * 4 + q;
        if (row < n)
          featb[(size_t)row * 256 + nf * 16 + r0] = f2bf(acc[nf][mf][q]);
      }
}

// el/er from bf16 feat. 4 rows/block; lane covers cols lane*4..lane*4+3
// (head = lane>>3); 8-lane xor reduce per head.
__global__ __launch_bounds__(256) void k_el(const unsigned short* __restrict__ featb,
                                            const float* __restrict__ al,
                                            const float* __restrict__ ar,
                                            float* __restrict__ el,
                                            float* __restrict__ er, int n) {
  int row = blockIdx.x * 4 + (threadIdx.x >> 6);
  int lane = threadIdx.x & 63;
  if (row >= n) return;
  ushort4 v = *reinterpret_cast<const ushort4*>(featb + (size_t)row * 256 + lane * 4);
  float f0 = bf2f(v.x), f1 = bf2f(v.y), f2 = bf2f(v.z), f3 = bf2f(v.w);
  int c = lane * 4;
  float pl = f0 * al[c] + f1 * al[c + 1] + f2 * al[c + 2] + f3 * al[c + 3];
  float pr = f0 * ar[c] + f1 * ar[c + 1] + f2 * ar[c + 2] + f3 * ar[c + 3];
#pragma unroll
  for (int off = 1; off < 8; off <<= 1) {
    pl += __shfl_xor(pl, off, 64);
    pr += __shfl_xor(pr, off, 64);
  }
  if ((lane & 7) == 0) {
    el[row * 8 + (lane >> 3)] = pl;
    er[row * 8 + (lane >> 3)] = pr;
  }
}

// Block per dst node; 4 waves x wave-per-edge; bf16 feat gather (8B/lane).
__global__ __launch_bounds__(256) void k_agg1(
    const unsigned short* __restrict__ featb, const float* __restrict__ el,
    const float* __restrict__ er, const int* __restrict__ offs,
    const int* __restrict__ csr, const float* __restrict__ b1,
    unsigned short* __restrict__ hb, int n) {
  __shared__ int s_idx[CH];
  __shared__ float psum[4][256];
  __shared__ float pden[4][8];
  int dn = blockIdx.x;
  int tid = threadIdx.x;
  int w = tid >> 6, l = tid & 63;
  int hh = l >> 3;
  float erd = er[dn * 8 + hh];
  int beg = offs[dn], end = offs[dn + 1];
  float4 acc = {0.f, 0.f, 0.f, 0.f};
  float den = 0.f;
  for (int base = beg; base < end; base += CH) {
    int cnt = min(CH, end - base);
    __syncthreads();
    if (tid < cnt) s_idx[tid] = csr[base + tid];
    __syncthreads();
    for (int i = w; i < cnt; i += 4) {
      int s = s_idx[i];
      float ev = el[s * 8 + hh] + erd;
      ev = ev >= 0.f ? ev : 0.2f * ev;
      float ee = __expf(ev);
      den += ee;
      ushort4 fv = *reinterpret_cast<const ushort4*>(featb + (size_t)s * 256 + l * 4);
      acc.x = fmaf(ee, bf2f(fv.x), acc.x);
      acc.y = fmaf(ee, bf2f(fv.y), acc.y);
      acc.z = fmaf(ee, bf2f(fv.z), acc.z);
      acc.w = fmaf(ee, bf2f(fv.w), acc.w);
    }
  }
  *reinterpret_cast<float4*>(&psum[w][l * 4]) = acc;
  if ((l & 7) == 0) pden[w][hh] = den;
  __syncthreads();
  int j = tid;
  float num = psum[0][j] + psum[1][j] + psum[2][j] + psum[3][j];
  int jh = j >> 5;
  float d = pden[0][jh] + pden[1][jh] + pden[2][jh] + pden[3][jh];
  float v = num / fmaxf(d, 1e-16f) + b1[j];
  v = v > 0.f ? v : expm1f(v);
  hb[(size_t)dn * 256 + j] = f2bf(v);
}

// feat2 = h_bf16 @ W2 (256x2), one wave per node, fused el2/er2.
__global__ __launch_bounds__(256) void k_gemm2(
    const unsigned short* __restrict__ hb, const float* __restrict__ W2,
    const float* __restrict__ al2, const float* __restrict__ ar2,
    float* __restrict__ feat2, float* __restrict__ el2, float* __restrict__ er2,
    int n) {
  __shared__ float w2s[512];
  for (int i = threadIdx.x; i < 512; i += 256) w2s[i] = W2[i];
  __syncthreads();
  int wave = threadIdx.x >> 6, lane = threadIdx.x & 63;
  int node = blockIdx.x * 4 + wave;
  if (node >= n) return;
  ushort4 hv = *reinterpret_cast<const ushort4*>(hb + (size_t)node * 256 + lane * 4);
  float h0 = bf2f(hv.x), h1 = bf2f(hv.y), h2 = bf2f(hv.z), h3 = bf2f(hv.w);
  int kb = lane * 4;
  float a0 = 0.f, a1 = 0.f;
  a0 = fmaf(h0, w2s[(kb + 0) * 2 + 0], a0);
  a1 = fmaf(h0, w2s[(kb + 0) * 2 + 1], a1);
  a0 = fmaf(h1, w2s[(kb + 1) * 2 + 0], a0);
  a1 = fmaf(h1, w2s[(kb + 1) * 2 + 1], a1);
  a0 = fmaf(h2, w2s[(kb + 2) * 2 + 0], a0);
  a1 = fmaf(h2, w2s[(kb + 2) * 2 + 1], a1);
  a0 = fmaf(h3, w2s[(kb + 3) * 2 + 0], a0);
  a1 = fmaf(h3, w2s[(kb + 3) * 2 + 1], a1);
#pragma unroll
  for (int off = 32; off; off >>= 1) {
    a0 += __shfl_xor(a0, off, 64);
    a1 += __shfl_xor(a1, off, 64);
  }
  if (lane == 0) {
    feat2[node * 2 + 0] = a0;
    feat2[node * 2 + 1] = a1;
    el2[node] = a0 * al2[0] + a1 * al2[1];
    er2[node] = a0 * ar2[0] + a1 * ar2[1];
  }
}

// Wave per dst node; lanes = edges; shuffle reduce; fused log_softmax.
__global__ __launch_bounds__(256) void k_agg2(
    const float* __restrict__ feat2, const float* __restrict__ el2,
    const float* __restrict__ er2, const int* __restrict__ offs,
    const int* __restrict__ csr, const float* __restrict__ b2,
    float* __restrict__ out, int n) {
  int dn = blockIdx.x * 4 + (threadIdx.x >> 6);
  int l = threadIdx.x & 63;
  if (dn >= n) return;
  float erd = er2[dn];
  int beg = offs[dn], end = offs[dn + 1];
  float den = 0.f, a0 = 0.f, a1 = 0.f;
  for (int e = beg + l; e < end; e += 64) {
    int s = csr[e];
    float ev = el2[s] + erd;
    ev = ev >= 0.f ? ev : 0.2f * ev;
    float ee = __expf(ev);
    den += ee;
    float2 f2 = *reinterpret_cast<const float2*>(feat2 + (size_t)s * 2);
    a0 = fmaf(ee, f2.x, a0);
    a1 = fmaf(ee, f2.y, a1);
  }
#pragma unroll
  for (int off = 32; off; off >>= 1) {
    den += __shfl_xor(den, off, 64);
    a0 += __shfl_xor(a0, off, 64);
    a1 += __shfl_xor(a1, off, 64);
  }
  if (l == 0) {
    float inv = 1.f / fmaxf(den, 1e-16f);
    float z0 = a0 * inv + b2[0];
    float z1 = a1 * inv + b2[1];
    float m = fmaxf(z0, z1);
    float lse = m + logf(__expf(z0 - m) + __expf(z1 - m));
    out[dn * 2 + 0] = z0 - lse;
    out[dn * 2 + 1] = z1 - lse;
  }
}

extern "C" void kernel_launch(void* const* d_in, const int* in_sizes, int n_in,
                              void* d_out, int out_size, void* d_ws,
                              size_t ws_size, hipStream_t stream) {
  const float* x   = (const float*)d_in[0];
  const int* esrc  = (const int*)d_in[1];
  const int* edst  = (const int*)d_in[2];
  const float* W1  = (const float*)d_in[3];
  const float* al1 = (const float*)d_in[4];
  const float* ar1 = (const float*)d_in[5];
  const float* b1  = (const float*)d_in[6];
  const float* W2  = (const float*)d_in[7];
  const float* al2 = (const float*)d_in[8];
  const float* ar2 = (const float*)d_in[9];
  const float* b2  = (const float*)d_in[10];
  float* out = (float*)d_out;

  size_t off = 0;
  auto alloc = [&](size_t bytes) {
    void* p = (char*)d_ws + off;
    off += (bytes + 255) & ~(size_t)255;
    return p;
  };
  unsigned short* featb = (unsigned short*)alloc((size_t)NN * 256 * 2);
  unsigned short* hb    = (unsigned short*)alloc((size_t)NN * 256 * 2);
  unsigned short* W1p   = (unsigned short*)alloc((size_t)16 * 8 * 64 * 8 * 2);
  float* el1   = (float*)alloc((size_t)NN * 8 * 4);
  float* er1   = (float*)alloc((size_t)NN * 8 * 4);
  float* feat2 = (float*)alloc((size_t)NN * 2 * 4);
  float* el2   = (float*)alloc((size_t)NN * 4);
  float* er2   = (float*)alloc((size_t)NN * 4);
  int* counts  = (int*)alloc((size_t)NN * 4);
  int* offs    = (int*)alloc((size_t)(NN + 1) * 4);
  int* cursor  = (int*)alloc((size_t)NN * 4);
  int* csr     = (int*)alloc((size_t)NE * 4);
  int* btot    = (int*)alloc(256 * 4);
  int* bofs    = (int*)alloc(256 * 4);

  const int NB = (NN + 255) / 256;  // 196

  hipMemsetAsync(counts, 0, (size_t)NN * 4, stream);
  k_hist<<<2048, 256, 0, stream>>>(edst, counts, NE);
  k_scan1<<<NB, 256, 0, stream>>>(counts, offs, btot, NN);
  k_scan2<<<1, 256, 0, stream>>>(btot, bofs, offs, NB, NN);
  k_scan3<<<NB, 256, 0, stream>>>(offs, bofs, cursor, NN);
  k_scatter<<<2048, 256, 0, stream>>>(edst, esrc, cursor, csr, NE);

  k_packw<<<32, 256, 0, stream>>>(W1, W1p);
  k_gemm1m<<<(NN / 32 + 4) / 4, 256, 0, stream>>>(x, W1p, featb, NN);
  k_el<<<(NN + 3) / 4, 256, 0, stream>>>(featb, al1, ar1, el1, er1, NN);
  k_agg1<<<NN, 256, 0, stream>>>(featb, el1, er1, offs, csr, b1, hb, NN);
  k_gemm2<<<(NN + 3) / 4, 256, 0, stream>>>(hb, W2, al2, ar2, feat2, el2, er2,
                                            NN);
  k_agg2<<<(NN + 3) / 4, 256, 0, stream>>>(feat2, el2, er2, offs, csr, b2, out,
                                           NN);
}

// Round 7
// 427.808 us; speedup vs baseline: 2.4798x; 1.0059x over previous
//
#include <hip/hip_runtime.h>

// GAT 2-layer. N=50000, E=1.6M. L1: 256->8x32 (bf16 MFMA), L2: 256->2.
// CSR by dst holds src ids. feat1 bf16. agg1: chunk-staged ee precompute
// (exp once per edge-head, not 8x), fused h@W2 epilogue -> node4 packed
// {feat2.x, feat2.y, el2, er2}; h never materialized.

#define NN 50000
#define NE 1600000
#define CH 256  // edge chunk staged in LDS (agg1)

typedef __attribute__((ext_vector_type(8))) short short8;
typedef __attribute__((ext_vector_type(4))) float f32x4;

__device__ inline unsigned short f2bf(float f) {
  unsigned int u = __float_as_uint(f);
  unsigned int r = (u + 0x7fffu + ((u >> 16) & 1u)) >> 16;
  return (unsigned short)r;
}
__device__ inline float bf2f(unsigned short h) {
  return __uint_as_float(((unsigned int)h) << 16);
}
__device__ inline float lrelu_exp(float v) {
  v = v >= 0.f ? v : 0.2f * v;
  return __expf(v);
}

__global__ __launch_bounds__(256) void k_hist(const int* __restrict__ dst,
                                              int* __restrict__ counts, int E) {
  for (int i = blockIdx.x * blockDim.x + threadIdx.x; i < E;
       i += gridDim.x * blockDim.x)
    atomicAdd(&counts[dst[i]], 1);
}

__global__ __launch_bounds__(256) void k_scan1(const int* __restrict__ counts,
                                               int* __restrict__ offs,
                                               int* __restrict__ btot, int n) {
  __shared__ int buf[256];
  int tid = threadIdx.x;
  int i = blockIdx.x * 256 + tid;
  int v = (i < n) ? counts[i] : 0;
  buf[tid] = v;
  __syncthreads();
  for (int off = 1; off < 256; off <<= 1) {
    int t = (tid >= off) ? buf[tid - off] : 0;
    __syncthreads();
    buf[tid] += t;
    __syncthreads();
  }
  if (i < n) offs[i] = buf[tid] - v;
  if (tid == 255) btot[blockIdx.x] = buf[255];
}

__global__ __launch_bounds__(256) void k_scan2(int* __restrict__ btot,
                                               int* __restrict__ bofs,
                                               int* __restrict__ offs, int nb,
                                               int n) {
  __shared__ int buf[256];
  int tid = threadIdx.x;
  int v = (tid < nb) ? btot[tid] : 0;
  buf[tid] = v;
  __syncthreads();
  for (int off = 1; off < 256; off <<= 1) {
    int t = (tid >= off) ? buf[tid - off] : 0;
    __syncthreads();
    buf[tid] += t;
    __syncthreads();
  }
  if (tid < nb) bofs[tid] = buf[tid] - v;
  if (tid == 255) offs[n] = buf[255];
}

__global__ __launch_bounds__(256) void k_scan3(int* __restrict__ offs,
                                               const int* __restrict__ bofs,
                                               int* __restrict__ cursor, int n) {
  int i = blockIdx.x * 256 + threadIdx.x;
  if (i < n) {
    int v = offs[i] + bofs[blockIdx.x];
    offs[i] = v;
    cursor[i] = v;
  }
}

__global__ __launch_bounds__(256) void k_scatter(const int* __restrict__ dst,
                                                 const int* __restrict__ src,
                                                 int* __restrict__ cursor,
                                                 int* __restrict__ csr, int E) {
  for (int i = blockIdx.x * blockDim.x + threadIdx.x; i < E;
       i += gridDim.x * blockDim.x) {
    int p = atomicAdd(&cursor[dst[i]], 1);
    csr[p] = src[i];
  }
}

// Pack W1 (256x256 f32 row-major [k][n]) into MFMA B-fragment order, bf16.
__global__ __launch_bounds__(256) void k_packw(const float* __restrict__ W1,
                                               unsigned short* __restrict__ W1p) {
  int idx = blockIdx.x * 256 + threadIdx.x;  // 8192 total
  int nf = idx >> 9, rem = idx & 511;
  int ks = rem >> 6, lane = rem & 63;
  int n = nf * 16 + (lane & 15);
  int kb = ks * 32 + (lane >> 4) * 8;
#pragma unroll
  for (int j = 0; j < 8; ++j)
    W1p[(size_t)idx * 8 + j] = f2bf(W1[(kb + j) * 256 + n]);
}

// MFMA GEMM: feat_bf16 = bf16(x) @ bf16(W1). Wave: 32 rows x 256 cols.
__global__ __launch_bounds__(256) void k_gemm1m(
    const float* __restrict__ x, const unsigned short* __restrict__ W1p,
    unsigned short* __restrict__ featb, int n) {
  int w = threadIdx.x >> 6, lane = threadIdx.x & 63;
  int tile = (blockIdx.x * 4 + w) * 32;
  if (tile >= n) return;
  int r0 = lane & 15, kgrp = lane >> 4;
  f32x4 acc[16][2];
#pragma unroll
  for (int nf = 0; nf < 16; ++nf)
#pragma unroll
    for (int mf = 0; mf < 2; ++mf) acc[nf][mf] = (f32x4){0.f, 0.f, 0.f, 0.f};

  for (int ks = 0; ks < 8; ++ks) {
    int kb = ks * 32 + kgrp * 8;
    short8 a0, a1;
    {
      int row = tile + r0;
      const float* p = x + (size_t)row * 256 + kb;
      float4 v0 = *reinterpret_cast<const float4*>(p);
      float4 v1 = *reinterpret_cast<const float4*>(p + 4);
      a0[0] = (short)f2bf(v0.x); a0[1] = (short)f2bf(v0.y);
      a0[2] = (short)f2bf(v0.z); a0[3] = (short)f2bf(v0.w);
      a0[4] = (short)f2bf(v1.x); a0[5] = (short)f2bf(v1.y);
      a0[6] = (short)f2bf(v1.z); a0[7] = (short)f2bf(v1.w);
    }
    {
      int row = tile + 16 + r0;
      if (row < n) {
        const float* p = x + (size_t)row * 256 + kb;
        float4 v0 = *reinterpret_cast<const float4*>(p);
        float4 v1 = *reinterpret_cast<const float4*>(p + 4);
        a1[0] = (short)f2bf(v0.x); a1[1] = (short)f2bf(v0.y);
        a1[2] = (short)f2bf(v0.z); a1[3] = (short)f2bf(v0.w);
        a1[4] = (short)f2bf(v1.x); a1[5] = (short)f2bf(v1.y);
        a1[6] = (short)f2bf(v1.z); a1[7] = (short)f2bf(v1.w);
      } else {
#pragma unroll
        for (int j = 0; j < 8; ++j) a1[j] = 0;
      }
    }
#pragma unroll
    for (int nf = 0; nf < 16; ++nf) {
      short8 b = *reinterpret_cast<const short8*>(
          W1p + ((size_t)(nf * 8 + ks) * 64 + lane) * 8);
      acc[nf][0] = __builtin_amdgcn_mfma_f32_16x16x32_bf16(a0, b, acc[nf][0], 0, 0, 0);
      acc[nf][1] = __builtin_amdgcn_mfma_f32_16x16x32_bf16(a1, b, acc[nf][1], 0, 0, 0);
    }
  }
#pragma unroll
  for (int nf = 0; nf < 16; ++nf)
#pragma unroll
    for (int mf = 0; mf < 2; ++mf)
#pragma unroll
      for (int q = 0; q < 4; ++q) {
        int row = tile + mf * 16 + kgrp * 4 + q;
        if (row < n)
          featb[(size_t)row * 256 + nf * 16 + r0] = f2bf(acc[nf][mf][q]);
      }
}

// el/er from bf16 feat. 4 rows/block; 8-lane xor reduce per head.
__global__ __launch_bounds__(256) void k_el(const unsigned short* __restrict__ featb,
                                            const float* __restrict__ al,
                                            const float* __restrict__ ar,
                                            float* __restrict__ el,
                                            float* __restrict__ er, int n) {
  int row = blockIdx.x * 4 + (threadIdx.x >> 6);
  int lane = threadIdx.x & 63;
  if (row >= n) return;
  ushort4 v = *reinterpret_cast<const ushort4*>(featb + (size_t)row * 256 + lane * 4);
  float f0 = bf2f(v.x), f1 = bf2f(v.y), f2 = bf2f(v.z), f3 = bf2f(v.w);
  int c = lane * 4;
  float pl = f0 * al[c] + f1 * al[c + 1] + f2 * al[c + 2] + f3 * al[c + 3];
  float pr = f0 * ar[c] + f1 * ar[c + 1] + f2 * ar[c + 2] + f3 * ar[c + 3];
#pragma unroll
  for (int off = 1; off < 8; off <<= 1) {
    pl += __shfl_xor(pl, off, 64);
    pr += __shfl_xor(pr, off, 64);
  }
  if ((lane & 7) == 0) {
    el[row * 8 + (lane >> 3)] = pl;
    er[row * 8 + (lane >> 3)] = pr;
  }
}

// Block per dst node. Chunk staging precomputes ee per (edge,head) once.
// Inner: 4 waves x wave-per-edge, bf16 gather. Epilogue fuses +b1, ELU,
// h@W2, el2/er2 -> node4[dn] = {a0, a1, el2, er2}.
__global__ __launch_bounds__(256) void k_agg1(
    const unsigned short* __restrict__ featb, const float* __restrict__ el,
    const float* __restrict__ er, const int* __restrict__ offs,
    const int* __restrict__ csr, const float* __restrict__ b1,
    const float* __restrict__ W2, const float* __restrict__ al2,
    const float* __restrict__ ar2, float4* __restrict__ node4, int n) {
  __shared__ int s_idx[CH];
  __shared__ float s_ee[8 * 257];
  __shared__ float psum[4][256];
  __shared__ float pden[4][8];
  __shared__ float w2s[512];
  __shared__ float red[4][2];
  int dn = blockIdx.x;
  int tid = threadIdx.x;
  int w = tid >> 6, l = tid & 63;
  int hh = l >> 3;
  for (int i = tid; i < 512; i += 256) w2s[i] = W2[i];
  // er row of dn (uniform)
  float4 er_lo = *reinterpret_cast<const float4*>(er + dn * 8);
  float4 er_hi = *reinterpret_cast<const float4*>(er + dn * 8 + 4);
  int beg = offs[dn], end = offs[dn + 1];
  float4 acc = {0.f, 0.f, 0.f, 0.f};
  float den = 0.f;
  for (int base = beg; base < end; base += CH) {
    int cnt = min(CH, end - base);
    __syncthreads();
    if (tid < cnt) {
      int s = csr[base + tid];
      s_idx[tid] = s;
      float4 e0 = *reinterpret_cast<const float4*>(el + s * 8);
      float4 e1 = *reinterpret_cast<const float4*>(el + s * 8 + 4);
      s_ee[0 * 257 + tid] = lrelu_exp(e0.x + er_lo.x);
      s_ee[1 * 257 + tid] = lrelu_exp(e0.y + er_lo.y);
      s_ee[2 * 257 + tid] = lrelu_exp(e0.z + er_lo.z);
      s_ee[3 * 257 + tid] = lrelu_exp(e0.w + er_lo.w);
      s_ee[4 * 257 + tid] = lrelu_exp(e1.x + er_hi.x);
      s_ee[5 * 257 + tid] = lrelu_exp(e1.y + er_hi.y);
      s_ee[6 * 257 + tid] = lrelu_exp(e1.z + er_hi.z);
      s_ee[7 * 257 + tid] = lrelu_exp(e1.w + er_hi.w);
    }
    __syncthreads();
    for (int i = w; i < cnt; i += 4) {
      int s = s_idx[i];
      float ee = s_ee[hh * 257 + i];
      den += ee;
      ushort4 fv = *reinterpret_cast<const ushort4*>(featb + (size_t)s * 256 + l * 4);
      acc.x = fmaf(ee, bf2f(fv.x), acc.x);
      acc.y = fmaf(ee, bf2f(fv.y), acc.y);
      acc.z = fmaf(ee, bf2f(fv.z), acc.z);
      acc.w = fmaf(ee, bf2f(fv.w), acc.w);
    }
  }
  *reinterpret_cast<float4*>(&psum[w][l * 4]) = acc;
  if ((l & 7) == 0) pden[w][hh] = den;
  __syncthreads();
  int j = tid;
  float num = psum[0][j] + psum[1][j] + psum[2][j] + psum[3][j];
  int jh = j >> 5;
  float d = pden[0][jh] + pden[1][jh] + pden[2][jh] + pden[3][jh];
  float v = num / fmaxf(d, 1e-16f) + b1[j];
  v = v > 0.f ? v : expm1f(v);  // h[dn][j]
  // fused h @ W2 (256x2)
  float p0 = v * w2s[j * 2 + 0];
  float p1 = v * w2s[j * 2 + 1];
#pragma unroll
  for (int off = 32; off; off >>= 1) {
    p0 += __shfl_xor(p0, off, 64);
    p1 += __shfl_xor(p1, off, 64);
  }
  if (l == 0) { red[w][0] = p0; red[w][1] = p1; }
  __syncthreads();
  if (tid == 0) {
    float a0 = red[0][0] + red[1][0] + red[2][0] + red[3][0];
    float a1 = red[0][1] + red[1][1] + red[2][1] + red[3][1];
    float e2 = a0 * al2[0] + a1 * al2[1];
    float r2 = a0 * ar2[0] + a1 * ar2[1];
    node4[dn] = make_float4(a0, a1, e2, r2);
  }
}

// Wave per dst node; single float4 gather per edge; fused log_softmax.
__global__ __launch_bounds__(256) void k_agg2(
    const float4* __restrict__ node4, const int* __restrict__ offs,
    const int* __restrict__ csr, const float* __restrict__ b2,
    float* __restrict__ out, int n) {
  int dn = blockIdx.x * 4 + (threadIdx.x >> 6);
  int l = threadIdx.x & 63;
  if (dn >= n) return;
  float erd = node4[dn].w;
  int beg = offs[dn], end = offs[dn + 1];
  float den = 0.f, a0 = 0.f, a1 = 0.f;
  for (int e = beg + l; e < end; e += 64) {
    int s = csr[e];
    float4 n4 = node4[s];
    float ev = n4.z + erd;
    ev = ev >= 0.f ? ev : 0.2f * ev;
    float ee = __expf(ev);
    den += ee;
    a0 = fmaf(ee, n4.x, a0);
    a1 = fmaf(ee, n4.y, a1);
  }
#pragma unroll
  for (int off = 32; off; off >>= 1) {
    den += __shfl_xor(den, off, 64);
    a0 += __shfl_xor(a0, off, 64);
    a1 += __shfl_xor(a1, off, 64);
  }
  if (l == 0) {
    float inv = 1.f / fmaxf(den, 1e-16f);
    float z0 = a0 * inv + b2[0];
    float z1 = a1 * inv + b2[1];
    float m = fmaxf(z0, z1);
    float lse = m + logf(__expf(z0 - m) + __expf(z1 - m));
    out[dn * 2 + 0] = z0 - lse;
    out[dn * 2 + 1] = z1 - lse;
  }
}

extern "C" void kernel_launch(void* const* d_in, const int* in_sizes, int n_in,
                              void* d_out, int out_size, void* d_ws,
                              size_t ws_size, hipStream_t stream) {
  const float* x   = (const float*)d_in[0];
  const int* esrc  = (const int*)d_in[1];
  const int* edst  = (const int*)d_in[2];
  const float* W1  = (const float*)d_in[3];
  const float* al1 = (const float*)d_in[4];
  const float* ar1 = (const float*)d_in[5];
  const float* b1  = (const float*)d_in[6];
  const float* W2  = (const float*)d_in[7];
  const float* al2 = (const float*)d_in[8];
  const float* ar2 = (const float*)d_in[9];
  const float* b2  = (const float*)d_in[10];
  float* out = (float*)d_out;

  size_t off = 0;
  auto alloc = [&](size_t bytes) {
    void* p = (char*)d_ws + off;
    off += (bytes + 255) & ~(size_t)255;
    return p;
  };
  unsigned short* featb = (unsigned short*)alloc((size_t)NN * 256 * 2);
  unsigned short* W1p   = (unsigned short*)alloc((size_t)16 * 8 * 64 * 8 * 2);
  float* el1    = (float*)alloc((size_t)NN * 8 * 4);
  float* er1    = (float*)alloc((size_t)NN * 8 * 4);
  float4* node4 = (float4*)alloc((size_t)NN * 16);
  int* counts   = (int*)alloc((size_t)NN * 4);
  int* offs     = (int*)alloc((size_t)(NN + 1) * 4);
  int* cursor   = (int*)alloc((size_t)NN * 4);
  int* csr      = (int*)alloc((size_t)NE * 4);
  int* btot     = (int*)alloc(256 * 4);
  int* bofs     = (int*)alloc(256 * 4);

  const int NB = (NN + 255) / 256;  // 196

  hipMemsetAsync(counts, 0, (size_t)NN * 4, stream);
  k_hist<<<2048, 256, 0, stream>>>(edst, counts, NE);
  k_scan1<<<NB, 256, 0, stream>>>(counts, offs, btot, NN);
  k_scan2<<<1, 256, 0, stream>>>(btot, bofs, offs, NB, NN);
  k_scan3<<<NB, 256, 0, stream>>>(offs, bofs, cursor, NN);
  k_scatter<<<2048, 256, 0, stream>>>(edst, esrc, cursor, csr, NE);

  k_packw<<<32, 256, 0, stream>>>(W1, W1p);
  k_gemm1m<<<(NN / 32 + 4) / 4, 256, 0, stream>>>(x, W1p, featb, NN);
  k_el<<<(NN + 3) / 4, 256, 0, stream>>>(featb, al1, ar1, el1, er1, NN);
  k_agg1<<<NN, 256, 0, stream>>>(featb, el1, er1, offs, csr, b1, W2, al2, ar2,
                                 node4, NN);
  k_agg2<<<(NN + 3) / 4, 256, 0, stream>>>(node4, offs, csr, b2, out, NN);
}

// Round 8
// 386.282 us; speedup vs baseline: 2.7464x; 1.1075x over previous
//
#include <hip/hip_runtime.h>

// GAT 2-layer. N=50000, E=1.6M (avg degree 32). L1: 256->8x32 (bf16 MFMA).
// agg1: WAVE per dst node (no LDS/barriers; degree too small for blocks).
// 8-edge groups: lane=(edge e=l>>3, head h=l&7) computes exp once; s/ee
// broadcast via shuffle. den needs no reduce (every lane sums all edges).
// Fused h@W2 epilogue -> node4 {feat2.x, feat2.y, el2, er2}.

#define NN 50000
#define NE 1600000

typedef __attribute__((ext_vector_type(8))) short short8;
typedef __attribute__((ext_vector_type(4))) float f32x4;

__device__ inline unsigned short f2bf(float f) {
  unsigned int u = __float_as_uint(f);
  unsigned int r = (u + 0x7fffu + ((u >> 16) & 1u)) >> 16;
  return (unsigned short)r;
}
__device__ inline float bf2f(unsigned short h) {
  return __uint_as_float(((unsigned int)h) << 16);
}
__device__ inline float lrelu_exp(float v) {
  v = v >= 0.f ? v : 0.2f * v;
  return __expf(v);
}

__global__ __launch_bounds__(256) void k_hist(const int* __restrict__ dst,
                                              int* __restrict__ counts, int E) {
  for (int i = blockIdx.x * blockDim.x + threadIdx.x; i < E;
       i += gridDim.x * blockDim.x)
    atomicAdd(&counts[dst[i]], 1);
}

__global__ __launch_bounds__(256) void k_scan1(const int* __restrict__ counts,
                                               int* __restrict__ offs,
                                               int* __restrict__ btot, int n) {
  __shared__ int buf[256];
  int tid = threadIdx.x;
  int i = blockIdx.x * 256 + tid;
  int v = (i < n) ? counts[i] : 0;
  buf[tid] = v;
  __syncthreads();
  for (int off = 1; off < 256; off <<= 1) {
    int t = (tid >= off) ? buf[tid - off] : 0;
    __syncthreads();
    buf[tid] += t;
    __syncthreads();
  }
  if (i < n) offs[i] = buf[tid] - v;
  if (tid == 255) btot[blockIdx.x] = buf[255];
}

__global__ __launch_bounds__(256) void k_scan2(int* __restrict__ btot,
                                               int* __restrict__ bofs,
                                               int* __restrict__ offs, int nb,
                                               int n) {
  __shared__ int buf[256];
  int tid = threadIdx.x;
  int v = (tid < nb) ? btot[tid] : 0;
  buf[tid] = v;
  __syncthreads();
  for (int off = 1; off < 256; off <<= 1) {
    int t = (tid >= off) ? buf[tid - off] : 0;
    __syncthreads();
    buf[tid] += t;
    __syncthreads();
  }
  if (tid < nb) bofs[tid] = buf[tid] - v;
  if (tid == 255) offs[n] = buf[255];
}

__global__ __launch_bounds__(256) void k_scan3(int* __restrict__ offs,
                                               const int* __restrict__ bofs,
                                               int* __restrict__ cursor, int n) {
  int i = blockIdx.x * 256 + threadIdx.x;
  if (i < n) {
    int v = offs[i] + bofs[blockIdx.x];
    offs[i] = v;
    cursor[i] = v;
  }
}

__global__ __launch_bounds__(256) void k_scatter(const int* __restrict__ dst,
                                                 const int* __restrict__ src,
                                                 int* __restrict__ cursor,
                                                 int* __restrict__ csr, int E) {
  for (int i = blockIdx.x * blockDim.x + threadIdx.x; i < E;
       i += gridDim.x * blockDim.x) {
    int p = atomicAdd(&cursor[dst[i]], 1);
    csr[p] = src[i];
  }
}

// Pack W1 (256x256 f32 row-major [k][n]) into MFMA B-fragment order, bf16.
__global__ __launch_bounds__(256) void k_packw(const float* __restrict__ W1,
                                               unsigned short* __restrict__ W1p) {
  int idx = blockIdx.x * 256 + threadIdx.x;  // 8192 total
  int nf = idx >> 9, rem = idx & 511;
  int ks = rem >> 6, lane = rem & 63;
  int n = nf * 16 + (lane & 15);
  int kb = ks * 32 + (lane >> 4) * 8;
#pragma unroll
  for (int j = 0; j < 8; ++j)
    W1p[(size_t)idx * 8 + j] = f2bf(W1[(kb + j) * 256 + n]);
}

// MFMA GEMM: feat_bf16 = bf16(x) @ bf16(W1). Wave: 32 rows x 256 cols.
__global__ __launch_bounds__(256) void k_gemm1m(
    const float* __restrict__ x, const unsigned short* __restrict__ W1p,
    unsigned short* __restrict__ featb, int n) {
  int w = threadIdx.x >> 6, lane = threadIdx.x & 63;
  int tile = (blockIdx.x * 4 + w) * 32;
  if (tile >= n) return;
  int r0 = lane & 15, kgrp = lane >> 4;
  f32x4 acc[16][2];
#pragma unroll
  for (int nf = 0; nf < 16; ++nf)
#pragma unroll
    for (int mf = 0; mf < 2; ++mf) acc[nf][mf] = (f32x4){0.f, 0.f, 0.f, 0.f};

  for (int ks = 0; ks < 8; ++ks) {
    int kb = ks * 32 + kgrp * 8;
    short8 a0, a1;
    {
      int row = tile + r0;
      const float* p = x + (size_t)row * 256 + kb;
      float4 v0 = *reinterpret_cast<const float4*>(p);
      float4 v1 = *reinterpret_cast<const float4*>(p + 4);
      a0[0] = (short)f2bf(v0.x); a0[1] = (short)f2bf(v0.y);
      a0[2] = (short)f2bf(v0.z); a0[3] = (short)f2bf(v0.w);
      a0[4] = (short)f2bf(v1.x); a0[5] = (short)f2bf(v1.y);
      a0[6] = (short)f2bf(v1.z); a0[7] = (short)f2bf(v1.w);
    }
    {
      int row = tile + 16 + r0;
      if (row < n) {
        const float* p = x + (size_t)row * 256 + kb;
        float4 v0 = *reinterpret_cast<const float4*>(p);
        float4 v1 = *reinterpret_cast<const float4*>(p + 4);
        a1[0] = (short)f2bf(v0.x); a1[1] = (short)f2bf(v0.y);
        a1[2] = (short)f2bf(v0.z); a1[3] = (short)f2bf(v0.w);
        a1[4] = (short)f2bf(v1.x); a1[5] = (short)f2bf(v1.y);
        a1[6] = (short)f2bf(v1.z); a1[7] = (short)f2bf(v1.w);
      } else {
#pragma unroll
        for (int j = 0; j < 8; ++j) a1[j] = 0;
      }
    }
#pragma unroll
    for (int nf = 0; nf < 16; ++nf) {
      short8 b = *reinterpret_cast<const short8*>(
          W1p + ((size_t)(nf * 8 + ks) * 64 + lane) * 8);
      acc[nf][0] = __builtin_amdgcn_mfma_f32_16x16x32_bf16(a0, b, acc[nf][0], 0, 0, 0);
      acc[nf][1] = __builtin_amdgcn_mfma_f32_16x16x32_bf16(a1, b, acc[nf][1], 0, 0, 0);
    }
  }
#pragma unroll
  for (int nf = 0; nf < 16; ++nf)
#pragma unroll
    for (int mf = 0; mf < 2; ++mf)
#pragma unroll
      for (int q = 0; q < 4; ++q) {
        int row = tile + mf * 16 + kgrp * 4 + q;
        if (row < n)
          featb[(size_t)row * 256 + nf * 16 + r0] = f2bf(acc[nf][mf][q]);
      }
}

// el/er from bf16 feat. 4 rows/block; 8-lane xor reduce per head.
__global__ __launch_bounds__(256) void k_el(const unsigned short* __restrict__ featb,
                                            const float* __restrict__ al,
                                            const float* __restrict__ ar,
                                            float* __restrict__ el,
                                            float* __restrict__ er, int n) {
  int row = blockIdx.x * 4 + (threadIdx.x >> 6);
  int lane = threadIdx.x & 63;
  if (row >= n) return;
  ushort4 v = *reinterpret_cast<const ushort4*>(featb + (size_t)row * 256 + lane * 4);
  float f0 = bf2f(v.x), f1 = bf2f(v.y), f2 = bf2f(v.z), f3 = bf2f(v.w);
  int c = lane * 4;
  float pl = f0 * al[c] + f1 * al[c + 1] + f2 * al[c + 2] + f3 * al[c + 3];
  float pr = f0 * ar[c] + f1 * ar[c + 1] + f2 * ar[c + 2] + f3 * ar[c + 3];
#pragma unroll
  for (int off = 1; off < 8; off <<= 1) {
    pl += __shfl_xor(pl, off, 64);
    pr += __shfl_xor(pr, off, 64);
  }
  if ((lane & 7) == 0) {
    el[row * 8 + (lane >> 3)] = pl;
    er[row * 8 + (lane >> 3)] = pr;
  }
}

// Wave per dst node. Lane l owns cols l*4..l*4+3 (head hh=l>>3).
// 8-edge groups: lane (e=l>>3, h=l&7) computes ee once; shuffle-broadcast.
// den: every lane accumulates all edges' ee for its hh -> no reduction.
// Epilogue: +b1, ELU, h@W2, el2/er2 -> node4.
__global__ __launch_bounds__(256) void k_agg1(
    const unsigned short* __restrict__ featb, const float* __restrict__ el,
    const float* __restrict__ er, const int* __restrict__ offs,
    const int* __restrict__ csr, const float* __restrict__ b1,
    const float* __restrict__ W2, const float* __restrict__ al2,
    const float* __restrict__ ar2, float4* __restrict__ node4, int n) {
  int dn = blockIdx.x * 4 + (threadIdx.x >> 6);
  if (dn >= n) return;
  int l = threadIdx.x & 63;
  int hh = l >> 3;  // head of this lane's 4 output cols
  int h8 = l & 7;   // head for ee computation
  float erv = er[dn * 8 + h8];
  int beg = offs[dn], end = offs[dn + 1];
  float4 acc = {0.f, 0.f, 0.f, 0.f};
  float den = 0.f;
  int g = beg;
  for (; g + 8 <= end; g += 8) {
    int s_my = csr[g + (l >> 3)];
    float eev = lrelu_exp(el[s_my * 8 + h8] + erv);
#pragma unroll
    for (int e = 0; e < 8; ++e) {
      int s = __shfl(s_my, e * 8, 64);
      float ee = __shfl(eev, e * 8 + hh, 64);
      den += ee;
      ushort4 fv = *reinterpret_cast<const ushort4*>(featb + (size_t)s * 256 + l * 4);
      acc.x = fmaf(ee, bf2f(fv.x), acc.x);
      acc.y = fmaf(ee, bf2f(fv.y), acc.y);
      acc.z = fmaf(ee, bf2f(fv.z), acc.z);
      acc.w = fmaf(ee, bf2f(fv.w), acc.w);
    }
  }
  if (g < end) {
    int rem = end - g;
    int idx = g + (l >> 3);
    int s_my = csr[idx < end ? idx : end - 1];
    float eev = lrelu_exp(el[s_my * 8 + h8] + erv);
    for (int e = 0; e < rem; ++e) {
      int s = __shfl(s_my, e * 8, 64);
      float ee = __shfl(eev, e * 8 + hh, 64);
      den += ee;
      ushort4 fv = *reinterpret_cast<const ushort4*>(featb + (size_t)s * 256 + l * 4);
      acc.x = fmaf(ee, bf2f(fv.x), acc.x);
      acc.y = fmaf(ee, bf2f(fv.y), acc.y);
      acc.z = fmaf(ee, bf2f(fv.z), acc.z);
      acc.w = fmaf(ee, bf2f(fv.w), acc.w);
    }
  }
  // epilogue: h = ELU(acc/den + b1), then h @ W2 slice, wave reduce
  float4 bv = *reinterpret_cast<const float4*>(b1 + l * 4);
  float4 w2e = *reinterpret_cast<const float4*>(W2 + l * 8);      // j*2+0/1 for j=4l,4l+1
  float4 w2o = *reinterpret_cast<const float4*>(W2 + l * 8 + 4);  // j=4l+2,4l+3
  float inv = 1.f / fmaxf(den, 1e-16f);
  float v0 = acc.x * inv + bv.x; v0 = v0 > 0.f ? v0 : expm1f(v0);
  float v1 = acc.y * inv + bv.y; v1 = v1 > 0.f ? v1 : expm1f(v1);
  float v2 = acc.z * inv + bv.z; v2 = v2 > 0.f ? v2 : expm1f(v2);
  float v3 = acc.w * inv + bv.w; v3 = v3 > 0.f ? v3 : expm1f(v3);
  float p0 = v0 * w2e.x + v1 * w2e.z + v2 * w2o.x + v3 * w2o.z;
  float p1 = v0 * w2e.y + v1 * w2e.w + v2 * w2o.y + v3 * w2o.w;
#pragma unroll
  for (int off = 32; off; off >>= 1) {
    p0 += __shfl_xor(p0, off, 64);
    p1 += __shfl_xor(p1, off, 64);
  }
  if (l == 0) {
    float e2 = p0 * al2[0] + p1 * al2[1];
    float r2 = p0 * ar2[0] + p1 * ar2[1];
    node4[dn] = make_float4(p0, p1, e2, r2);
  }
}

// Wave per dst node; single float4 gather per edge; fused log_softmax.
__global__ __launch_bounds__(256) void k_agg2(
    const float4* __restrict__ node4, const int* __restrict__ offs,
    const int* __restrict__ csr, const float* __restrict__ b2,
    float* __restrict__ out, int n) {
  int dn = blockIdx.x * 4 + (threadIdx.x >> 6);
  int l = threadIdx.x & 63;
  if (dn >= n) return;
  float erd = node4[dn].w;
  int beg = offs[dn], end = offs[dn + 1];
  float den = 0.f, a0 = 0.f, a1 = 0.f;
  for (int e = beg + l; e < end; e += 64) {
    int s = csr[e];
    float4 n4 = node4[s];
    float ev = n4.z + erd;
    ev = ev >= 0.f ? ev : 0.2f * ev;
    float ee = __expf(ev);
    den += ee;
    a0 = fmaf(ee, n4.x, a0);
    a1 = fmaf(ee, n4.y, a1);
  }
#pragma unroll
  for (int off = 32; off; off >>= 1) {
    den += __shfl_xor(den, off, 64);
    a0 += __shfl_xor(a0, off, 64);
    a1 += __shfl_xor(a1, off, 64);
  }
  if (l == 0) {
    float inv = 1.f / fmaxf(den, 1e-16f);
    float z0 = a0 * inv + b2[0];
    float z1 = a1 * inv + b2[1];
    float m = fmaxf(z0, z1);
    float lse = m + logf(__expf(z0 - m) + __expf(z1 - m));
    out[dn * 2 + 0] = z0 - lse;
    out[dn * 2 + 1] = z1 - lse;
  }
}

extern "C" void kernel_launch(void* const* d_in, const int* in_sizes, int n_in,
                              void* d_out, int out_size, void* d_ws,
                              size_t ws_size, hipStream_t stream) {
  const float* x   = (const float*)d_in[0];
  const int* esrc  = (const int*)d_in[1];
  const int* edst  = (const int*)d_in[2];
  const float* W1  = (const float*)d_in[3];
  const float* al1 = (const float*)d_in[4];
  const float* ar1 = (const float*)d_in[5];
  const float* b1  = (const float*)d_in[6];
  const float* W2  = (const float*)d_in[7];
  const float* al2 = (const float*)d_in[8];
  const float* ar2 = (const float*)d_in[9];
  const float* b2  = (const float*)d_in[10];
  float* out = (float*)d_out;

  size_t off = 0;
  auto alloc = [&](size_t bytes) {
    void* p = (char*)d_ws + off;
    off += (bytes + 255) & ~(size_t)255;
    return p;
  };
  unsigned short* featb = (unsigned short*)alloc((size_t)NN * 256 * 2);
  unsigned short* W1p   = (unsigned short*)alloc((size_t)16 * 8 * 64 * 8 * 2);
  float* el1    = (float*)alloc((size_t)NN * 8 * 4);
  float* er1    = (float*)alloc((size_t)NN * 8 * 4);
  float4* node4 = (float4*)alloc((size_t)NN * 16);
  int* counts   = (int*)alloc((size_t)NN * 4);
  int* offs     = (int*)alloc((size_t)(NN + 1) * 4);
  int* cursor   = (int*)alloc((size_t)NN * 4);
  int* csr      = (int*)alloc((size_t)NE * 4);
  int* btot     = (int*)alloc(256 * 4);
  int* bofs     = (int*)alloc(256 * 4);

  const int NB = (NN + 255) / 256;  // 196

  hipMemsetAsync(counts, 0, (size_t)NN * 4, stream);
  k_hist<<<2048, 256, 0, stream>>>(edst, counts, NE);
  k_scan1<<<NB, 256, 0, stream>>>(counts, offs, btot, NN);
  k_scan2<<<1, 256, 0, stream>>>(btot, bofs, offs, NB, NN);
  k_scan3<<<NB, 256, 0, stream>>>(offs, bofs, cursor, NN);
  k_scatter<<<2048, 256, 0, stream>>>(edst, esrc, cursor, csr, NE);

  k_packw<<<32, 256, 0, stream>>>(W1, W1p);
  k_gemm1m<<<(NN / 32 + 4) / 4, 256, 0, stream>>>(x, W1p, featb, NN);
  k_el<<<(NN + 3) / 4, 256, 0, stream>>>(featb, al1, ar1, el1, er1, NN);
  k_agg1<<<(NN + 3) / 4, 256, 0, stream>>>(featb, el1, er1, offs, csr, b1, W2,
                                           al2, ar2, node4, NN);
  k_agg2<<<(NN + 3) / 4, 256, 0, stream>>>(node4, offs, csr, b2, out, NN);
}

// Round 9
// 374.933 us; speedup vs baseline: 2.8295x; 1.0303x over previous
//
#include <hip/hip_runtime.h>

// GAT 2-layer. N=50000, E=1.6M (deg 32). L1: 256->8x32 (bf16 MFMA).
// CSR build: 8-way privatized counters (copy=blockIdx&7, copy-major layout),
// fire-and-forget hist, scan sums copies inline, mkcur builds per-copy
// cursors, scatter atomics hit 1/8 contention. 1 edge/thread exact grids.
// agg1: wave-per-node, shuffle-shared exp, fused h@W2 -> node4.

#define NN 50000
#define NE 1600000
#define CPAD 50048  // padded bin count per copy
#define EGRID 6250  // NE / 256 exactly

typedef __attribute__((ext_vector_type(8))) short short8;
typedef __attribute__((ext_vector_type(4))) float f32x4;

__device__ inline unsigned short f2bf(float f) {
  unsigned int u = __float_as_uint(f);
  unsigned int r = (u + 0x7fffu + ((u >> 16) & 1u)) >> 16;
  return (unsigned short)r;
}
__device__ inline float bf2f(unsigned short h) {
  return __uint_as_float(((unsigned int)h) << 16);
}
__device__ inline float lrelu_exp(float v) {
  v = v >= 0.f ? v : 0.2f * v;
  return __expf(v);
}

// fire-and-forget privatized histogram; 1 edge/thread, copy = blockIdx&7.
__global__ __launch_bounds__(256) void k_hist8(const int* __restrict__ dst,
                                               int* __restrict__ counts8, int E) {
  int i = blockIdx.x * 256 + threadIdx.x;
  if (i < E) atomicAdd(&counts8[(blockIdx.x & 7) * CPAD + dst[i]], 1);
}

// scan stage 1: per-block scan of T[i] = sum_c counts8[c][i].
__global__ __launch_bounds__(256) void k_scan1(const int* __restrict__ counts8,
                                               int* __restrict__ offs,
                                               int* __restrict__ btot, int n) {
  __shared__ int buf[256];
  int tid = threadIdx.x;
  int i = blockIdx.x * 256 + tid;
  int v = 0;
  if (i < n) {
#pragma unroll
    for (int c = 0; c < 8; ++c) v += counts8[c * CPAD + i];
  }
  buf[tid] = v;
  __syncthreads();
  for (int off = 1; off < 256; off <<= 1) {
    int t = (tid >= off) ? buf[tid - off] : 0;
    __syncthreads();
    buf[tid] += t;
    __syncthreads();
  }
  if (i < n) offs[i] = buf[tid] - v;
  if (tid == 255) btot[blockIdx.x] = buf[255];
}

__global__ __launch_bounds__(256) void k_scan2(int* __restrict__ btot,
                                               int* __restrict__ bofs,
                                               int* __restrict__ offs, int nb,
                                               int n) {
  __shared__ int buf[256];
  int tid = threadIdx.x;
  int v = (tid < nb) ? btot[tid] : 0;
  buf[tid] = v;
  __syncthreads();
  for (int off = 1; off < 256; off <<= 1) {
    int t = (tid >= off) ? buf[tid - off] : 0;
    __syncthreads();
    buf[tid] += t;
    __syncthreads();
  }
  if (tid < nb) bofs[tid] = buf[tid] - v;
  if (tid == 255) offs[n] = buf[255];
}

__global__ __launch_bounds__(256) void k_scan3(int* __restrict__ offs,
                                               const int* __restrict__ bofs,
                                               int n) {
  int i = blockIdx.x * 256 + threadIdx.x;
  if (i < n) offs[i] += bofs[blockIdx.x];
}

// cursor8[c][d] = offs[d] + sum_{c'<c} counts8[c'][d]; coalesced per copy.
__global__ __launch_bounds__(256) void k_mkcur(const int* __restrict__ offs,
                                               const int* __restrict__ counts8,
                                               int* __restrict__ cursor8, int n) {
  int i = blockIdx.x * 256 + threadIdx.x;
  if (i >= n) return;
  int cur = offs[i];
#pragma unroll
  for (int c = 0; c < 8; ++c) {
    cursor8[c * CPAD + i] = cur;
    cur += counts8[c * CPAD + i];
  }
}

// scatter with privatized cursors; MUST use same i->block mapping as k_hist8.
__global__ __launch_bounds__(256) void k_scatter8(const int* __restrict__ dst,
                                                  const int* __restrict__ src,
                                                  int* __restrict__ cursor8,
                                                  int* __restrict__ csr, int E) {
  int i = blockIdx.x * 256 + threadIdx.x;
  if (i < E) {
    int p = atomicAdd(&cursor8[(blockIdx.x & 7) * CPAD + dst[i]], 1);
    csr[p] = src[i];
  }
}

// Pack W1 (256x256 f32 row-major [k][n]) into MFMA B-fragment order, bf16.
__global__ __launch_bounds__(256) void k_packw(const float* __restrict__ W1,
                                               unsigned short* __restrict__ W1p) {
  int idx = blockIdx.x * 256 + threadIdx.x;  // 8192 total
  int nf = idx >> 9, rem = idx & 511;
  int ks = rem >> 6, lane = rem & 63;
  int n = nf * 16 + (lane & 15);
  int kb = ks * 32 + (lane >> 4) * 8;
#pragma unroll
  for (int j = 0; j < 8; ++j)
    W1p[(size_t)idx * 8 + j] = f2bf(W1[(kb + j) * 256 + n]);
}

// MFMA GEMM: feat_bf16 = bf16(x) @ bf16(W1). Wave: 32 rows x 256 cols.
__global__ __launch_bounds__(256) void k_gemm1m(
    const float* __restrict__ x, const unsigned short* __restrict__ W1p,
    unsigned short* __restrict__ featb, int n) {
  int w = threadIdx.x >> 6, lane = threadIdx.x & 63;
  int tile = (blockIdx.x * 4 + w) * 32;
  if (tile >= n) return;
  int r0 = lane & 15, kgrp = lane >> 4;
  f32x4 acc[16][2];
#pragma unroll
  for (int nf = 0; nf < 16; ++nf)
#pragma unroll
    for (int mf = 0; mf < 2; ++mf) acc[nf][mf] = (f32x4){0.f, 0.f, 0.f, 0.f};

  for (int ks = 0; ks < 8; ++ks) {
    int kb = ks * 32 + kgrp * 8;
    short8 a0, a1;
    {
      int row = tile + r0;
      const float* p = x + (size_t)row * 256 + kb;
      float4 v0 = *reinterpret_cast<const float4*>(p);
      float4 v1 = *reinterpret_cast<const float4*>(p + 4);
      a0[0] = (short)f2bf(v0.x); a0[1] = (short)f2bf(v0.y);
      a0[2] = (short)f2bf(v0.z); a0[3] = (short)f2bf(v0.w);
      a0[4] = (short)f2bf(v1.x); a0[5] = (short)f2bf(v1.y);
      a0[6] = (short)f2bf(v1.z); a0[7] = (short)f2bf(v1.w);
    }
    {
      int row = tile + 16 + r0;
      if (row < n) {
        const float* p = x + (size_t)row * 256 + kb;
        float4 v0 = *reinterpret_cast<const float4*>(p);
        float4 v1 = *reinterpret_cast<const float4*>(p + 4);
        a1[0] = (short)f2bf(v0.x); a1[1] = (short)f2bf(v0.y);
        a1[2] = (short)f2bf(v0.z); a1[3] = (short)f2bf(v0.w);
        a1[4] = (short)f2bf(v1.x); a1[5] = (short)f2bf(v1.y);
        a1[6] = (short)f2bf(v1.z); a1[7] = (short)f2bf(v1.w);
      } else {
#pragma unroll
        for (int j = 0; j < 8; ++j) a1[j] = 0;
      }
    }
#pragma unroll
    for (int nf = 0; nf < 16; ++nf) {
      short8 b = *reinterpret_cast<const short8*>(
          W1p + ((size_t)(nf * 8 + ks) * 64 + lane) * 8);
      acc[nf][0] = __builtin_amdgcn_mfma_f32_16x16x32_bf16(a0, b, acc[nf][0], 0, 0, 0);
      acc[nf][1] = __builtin_amdgcn_mfma_f32_16x16x32_bf16(a1, b, acc[nf][1], 0, 0, 0);
    }
  }
#pragma unroll
  for (int nf = 0; nf < 16; ++nf)
#pragma unroll
    for (int mf = 0; mf < 2; ++mf)
#pragma unroll
      for (int q = 0; q < 4; ++q) {
        int row = tile + mf * 16 + kgrp * 4 + q;
        if (row < n)
          featb[(size_t)row * 256 + nf * 16 + r0] = f2bf(acc[nf][mf][q]);
      }
}

// el/er from bf16 feat. 4 rows/block; 8-lane xor reduce per head.
__global__ __launch_bounds__(256) void k_el(const unsigned short* __restrict__ featb,
                                            const float* __restrict__ al,
                                            const float* __restrict__ ar,
                                            float* __restrict__ el,
                                            float* __restrict__ er, int n) {
  int row = blockIdx.x * 4 + (threadIdx.x >> 6);
  int lane = threadIdx.x & 63;
  if (row >= n) return;
  ushort4 v = *reinterpret_cast<const ushort4*>(featb + (size_t)row * 256 + lane * 4);
  float f0 = bf2f(v.x), f1 = bf2f(v.y), f2 = bf2f(v.z), f3 = bf2f(v.w);
  int c = lane * 4;
  float pl = f0 * al[c] + f1 * al[c + 1] + f2 * al[c + 2] + f3 * al[c + 3];
  float pr = f0 * ar[c] + f1 * ar[c + 1] + f2 * ar[c + 2] + f3 * ar[c + 3];
#pragma unroll
  for (int off = 1; off < 8; off <<= 1) {
    pl += __shfl_xor(pl, off, 64);
    pr += __shfl_xor(pr, off, 64);
  }
  if ((lane & 7) == 0) {
    el[row * 8 + (lane >> 3)] = pl;
    er[row * 8 + (lane >> 3)] = pr;
  }
}

// Wave per dst node. Lane l owns cols l*4..l*4+3 (head hh=l>>3).
// 8-edge groups: lane (e=l>>3, h=l&7) computes ee once; shuffle-broadcast.
__global__ __launch_bounds__(256) void k_agg1(
    const unsigned short* __restrict__ featb, const float* __restrict__ el,
    const float* __restrict__ er, const int* __restrict__ offs,
    const int* __restrict__ csr, const float* __restrict__ b1,
    const float* __restrict__ W2, const float* __restrict__ al2,
    const float* __restrict__ ar2, float4* __restrict__ node4, int n) {
  int dn = blockIdx.x * 4 + (threadIdx.x >> 6);
  if (dn >= n) return;
  int l = threadIdx.x & 63;
  int hh = l >> 3;  // head of this lane's 4 output cols
  int h8 = l & 7;   // head for ee computation
  float erv = er[dn * 8 + h8];
  int beg = offs[dn], end = offs[dn + 1];
  float4 acc = {0.f, 0.f, 0.f, 0.f};
  float den = 0.f;
  int g = beg;
  for (; g + 8 <= end; g += 8) {
    int s_my = csr[g + (l >> 3)];
    float eev = lrelu_exp(el[s_my * 8 + h8] + erv);
#pragma unroll
    for (int e = 0; e < 8; ++e) {
      int s = __shfl(s_my, e * 8, 64);
      float ee = __shfl(eev, e * 8 + hh, 64);
      den += ee;
      ushort4 fv = *reinterpret_cast<const ushort4*>(featb + (size_t)s * 256 + l * 4);
      acc.x = fmaf(ee, bf2f(fv.x), acc.x);
      acc.y = fmaf(ee, bf2f(fv.y), acc.y);
      acc.z = fmaf(ee, bf2f(fv.z), acc.z);
      acc.w = fmaf(ee, bf2f(fv.w), acc.w);
    }
  }
  if (g < end) {
    int rem = end - g;
    int idx = g + (l >> 3);
    int s_my = csr[idx < end ? idx : end - 1];
    float eev = lrelu_exp(el[s_my * 8 + h8] + erv);
    for (int e = 0; e < rem; ++e) {
      int s = __shfl(s_my, e * 8, 64);
      float ee = __shfl(eev, e * 8 + hh, 64);
      den += ee;
      ushort4 fv = *reinterpret_cast<const ushort4*>(featb + (size_t)s * 256 + l * 4);
      acc.x = fmaf(ee, bf2f(fv.x), acc.x);
      acc.y = fmaf(ee, bf2f(fv.y), acc.y);
      acc.z = fmaf(ee, bf2f(fv.z), acc.z);
      acc.w = fmaf(ee, bf2f(fv.w), acc.w);
    }
  }
  float4 bv = *reinterpret_cast<const float4*>(b1 + l * 4);
  float4 w2e = *reinterpret_cast<const float4*>(W2 + l * 8);
  float4 w2o = *reinterpret_cast<const float4*>(W2 + l * 8 + 4);
  float inv = 1.f / fmaxf(den, 1e-16f);
  float v0 = acc.x * inv + bv.x; v0 = v0 > 0.f ? v0 : expm1f(v0);
  float v1 = acc.y * inv + bv.y; v1 = v1 > 0.f ? v1 : expm1f(v1);
  float v2 = acc.z * inv + bv.z; v2 = v2 > 0.f ? v2 : expm1f(v2);
  float v3 = acc.w * inv + bv.w; v3 = v3 > 0.f ? v3 : expm1f(v3);
  float p0 = v0 * w2e.x + v1 * w2e.z + v2 * w2o.x + v3 * w2o.z;
  float p1 = v0 * w2e.y + v1 * w2e.w + v2 * w2o.y + v3 * w2o.w;
#pragma unroll
  for (int off = 32; off; off >>= 1) {
    p0 += __shfl_xor(p0, off, 64);
    p1 += __shfl_xor(p1, off, 64);
  }
  if (l == 0) {
    float e2 = p0 * al2[0] + p1 * al2[1];
    float r2 = p0 * ar2[0] + p1 * ar2[1];
    node4[dn] = make_float4(p0, p1, e2, r2);
  }
}

// Wave per dst node; single float4 gather per edge; fused log_softmax.
__global__ __launch_bounds__(256) void k_agg2(
    const float4* __restrict__ node4, const int* __restrict__ offs,
    const int* __restrict__ csr, const float* __restrict__ b2,
    float* __restrict__ out, int n) {
  int dn = blockIdx.x * 4 + (threadIdx.x >> 6);
  int l = threadIdx.x & 63;
  if (dn >= n) return;
  float erd = node4[dn].w;
  int beg = offs[dn], end = offs[dn + 1];
  float den = 0.f, a0 = 0.f, a1 = 0.f;
  for (int e = beg + l; e < end; e += 64) {
    int s = csr[e];
    float4 n4 = node4[s];
    float ev = n4.z + erd;
    ev = ev >= 0.f ? ev : 0.2f * ev;
    float ee = __expf(ev);
    den += ee;
    a0 = fmaf(ee, n4.x, a0);
    a1 = fmaf(ee, n4.y, a1);
  }
#pragma unroll
  for (int off = 32; off; off >>= 1) {
    den += __shfl_xor(den, off, 64);
    a0 += __shfl_xor(a0, off, 64);
    a1 += __shfl_xor(a1, off, 64);
  }
  if (l == 0) {
    float inv = 1.f / fmaxf(den, 1e-16f);
    float z0 = a0 * inv + b2[0];
    float z1 = a1 * inv + b2[1];
    float m = fmaxf(z0, z1);
    float lse = m + logf(__expf(z0 - m) + __expf(z1 - m));
    out[dn * 2 + 0] = z0 - lse;
    out[dn * 2 + 1] = z1 - lse;
  }
}

extern "C" void kernel_launch(void* const* d_in, const int* in_sizes, int n_in,
                              void* d_out, int out_size, void* d_ws,
                              size_t ws_size, hipStream_t stream) {
  const float* x   = (const float*)d_in[0];
  const int* esrc  = (const int*)d_in[1];
  const int* edst  = (const int*)d_in[2];
  const float* W1  = (const float*)d_in[3];
  const float* al1 = (const float*)d_in[4];
  const float* ar1 = (const float*)d_in[5];
  const float* b1  = (const float*)d_in[6];
  const float* W2  = (const float*)d_in[7];
  const float* al2 = (const float*)d_in[8];
  const float* ar2 = (const float*)d_in[9];
  const float* b2  = (const float*)d_in[10];
  float* out = (float*)d_out;

  size_t off = 0;
  auto alloc = [&](size_t bytes) {
    void* p = (char*)d_ws + off;
    off += (bytes + 255) & ~(size_t)255;
    return p;
  };
  unsigned short* featb = (unsigned short*)alloc((size_t)NN * 256 * 2);
  unsigned short* W1p   = (unsigned short*)alloc((size_t)16 * 8 * 64 * 8 * 2);
  float* el1    = (float*)alloc((size_t)NN * 8 * 4);
  float* er1    = (float*)alloc((size_t)NN * 8 * 4);
  float4* node4 = (float4*)alloc((size_t)NN * 16);
  int* counts8  = (int*)alloc((size_t)8 * CPAD * 4);
  int* cursor8  = (int*)alloc((size_t)8 * CPAD * 4);
  int* offs     = (int*)alloc((size_t)(NN + 1) * 4);
  int* csr      = (int*)alloc((size_t)NE * 4);
  int* btot     = (int*)alloc(256 * 4);
  int* bofs     = (int*)alloc(256 * 4);

  const int NB = (NN + 255) / 256;  // 196

  hipMemsetAsync(counts8, 0, (size_t)8 * CPAD * 4, stream);
  k_hist8<<<EGRID, 256, 0, stream>>>(edst, counts8, NE);
  k_scan1<<<NB, 256, 0, stream>>>(counts8, offs, btot, NN);
  k_scan2<<<1, 256, 0, stream>>>(btot, bofs, offs, NB, NN);
  k_scan3<<<NB, 256, 0, stream>>>(offs, bofs, NN);
  k_mkcur<<<NB, 256, 0, stream>>>(offs, counts8, cursor8, NN);
  k_scatter8<<<EGRID, 256, 0, stream>>>(edst, esrc, cursor8, csr, NE);

  k_packw<<<32, 256, 0, stream>>>(W1, W1p);
  k_gemm1m<<<(NN / 32 + 4) / 4, 256, 0, stream>>>(x, W1p, featb, NN);
  k_el<<<(NN + 3) / 4, 256, 0, stream>>>(featb, al1, ar1, el1, er1, NN);
  k_agg1<<<(NN + 3) / 4, 256, 0, stream>>>(featb, el1, er1, offs, csr, b1, W2,
                                           al2, ar2, node4, NN);
  k_agg2<<<(NN + 3) / 4, 256, 0, stream>>>(node4, offs, csr, b2, out, NN);
}

// Round 10
// 247.082 us; speedup vs baseline: 4.2937x; 1.5174x over previous
//
#include <hip/hip_runtime.h>

// GAT 2-layer. N=50000, E=1.6M (deg 32). L1: 256->8x32 (bf16 MFMA).
// CSR build = 2-level LDS counting sort (196 coarse buckets of 256 nodes):
//   bcount (LDS hist, 50K f&f atomics) -> bscan -> part (block-contiguous
//   bucket runs, 50K atomic-returns) -> build (per-bucket LDS hist+scan:
//   writes offs directly + places csr via LDS cursors).
// No per-edge global atomics anywhere.
// agg1: wave-per-node, shuffle-shared exp, fused h@W2 -> node4.

#define NN 50000
#define NE 1600000
#define NBK 196      // (NN+255)>>8 coarse buckets
#define PCH 6250     // edges per partition block; 256 blocks * 6250 = NE

typedef __attribute__((ext_vector_type(8))) short short8;
typedef __attribute__((ext_vector_type(4))) float f32x4;

__device__ inline unsigned short f2bf(float f) {
  unsigned int u = __float_as_uint(f);
  unsigned int r = (u + 0x7fffu + ((u >> 16) & 1u)) >> 16;
  return (unsigned short)r;
}
__device__ inline float bf2f(unsigned short h) {
  return __uint_as_float(((unsigned int)h) << 16);
}
__device__ inline float lrelu_exp(float v) {
  v = v >= 0.f ? v : 0.2f * v;
  return __expf(v);
}

// coarse bucket counts via LDS hist; ~196 f&f global atomics per block.
__global__ __launch_bounds__(256) void k_bcount(const int* __restrict__ dst,
                                                int* __restrict__ bcnt, int E) {
  __shared__ int h[NBK];
  int tid = threadIdx.x;
  for (int i = tid; i < NBK; i += 256) h[i] = 0;
  __syncthreads();
  int b0 = blockIdx.x * PCH;
  for (int k = tid; k < PCH; k += 256) {
    int i = b0 + k;
    if (i < E) atomicAdd(&h[dst[i] >> 8], 1);
  }
  __syncthreads();
  for (int i = tid; i < NBK; i += 256)
    if (h[i]) atomicAdd(&bcnt[i], h[i]);
}

// scan 196 bucket counts -> bbase[0..NBK] and bcursor.
__global__ __launch_bounds__(256) void k_bscan(const int* __restrict__ bcnt,
                                               int* __restrict__ bbase,
                                               int* __restrict__ bcursor) {
  __shared__ int buf[256];
  int tid = threadIdx.x;
  int v = (tid < NBK) ? bcnt[tid] : 0;
  buf[tid] = v;
  __syncthreads();
  for (int off = 1; off < 256; off <<= 1) {
    int t = (tid >= off) ? buf[tid - off] : 0;
    __syncthreads();
    buf[tid] += t;
    __syncthreads();
  }
  int excl = buf[tid] - v;
  if (tid < NBK) { bbase[tid] = excl; bcursor[tid] = excl; }
  if (tid == NBK - 1) bbase[NBK] = buf[tid];
}

// partition edges into coarse buckets; block reserves one contiguous run per
// bucket (atomic-return per (block,bucket)), writes ~256B sequential chunks.
__global__ __launch_bounds__(256) void k_part(const int* __restrict__ dst,
                                              const int* __restrict__ src,
                                              int* __restrict__ bcursor,
                                              int2* __restrict__ stage, int E) {
  __shared__ int h[NBK], base[NBK], lofs[NBK];
  int tid = threadIdx.x;
  for (int i = tid; i < NBK; i += 256) h[i] = 0;
  __syncthreads();
  int b0 = blockIdx.x * PCH;
  for (int k = tid; k < PCH; k += 256) {
    int i = b0 + k;
    if (i < E) atomicAdd(&h[dst[i] >> 8], 1);
  }
  __syncthreads();
  for (int i = tid; i < NBK; i += 256) {
    base[i] = h[i] ? atomicAdd(&bcursor[i], h[i]) : 0;
    lofs[i] = 0;
  }
  __syncthreads();
  for (int k = tid; k < PCH; k += 256) {
    int i = b0 + k;
    if (i < E) {
      int d = dst[i];
      int b = d >> 8;
      int r = atomicAdd(&lofs[b], 1);
      stage[base[b] + r] = make_int2(d, src[i]);
    }
  }
}

// per-bucket (256 nodes) LDS counting sort: writes offs slice + places csr.
__global__ __launch_bounds__(256) void k_build(const int2* __restrict__ stage,
                                               const int* __restrict__ bbase,
                                               int* __restrict__ offs,
                                               int* __restrict__ csr, int n,
                                               int E) {
  __shared__ int h[256], buf[256], cur[256];
  int b = blockIdx.x, tid = threadIdx.x;
  int beg = bbase[b], end = bbase[b + 1];
  h[tid] = 0;
  __syncthreads();
  for (int k = beg + tid; k < end; k += 256)
    atomicAdd(&h[stage[k].x & 255], 1);
  __syncthreads();
  int v = h[tid];
  buf[tid] = v;
  __syncthreads();
  for (int off = 1; off < 256; off <<= 1) {
    int t = (tid >= off) ? buf[tid - off] : 0;
    __syncthreads();
    buf[tid] += t;
    __syncthreads();
  }
  int excl = buf[tid] - v;
  int node = b * 256 + tid;
  if (node < n) offs[node] = beg + excl;
  if (b == 0 && tid == 0) offs[n] = E;
  cur[tid] = excl;
  __syncthreads();
  for (int k = beg + tid; k < end; k += 256) {
    int2 e = stage[k];
    int r = atomicAdd(&cur[e.x & 255], 1);
    csr[beg + r] = e.y;
  }
}

// Pack W1 (256x256 f32 row-major [k][n]) into MFMA B-fragment order, bf16.
__global__ __launch_bounds__(256) void k_packw(const float* __restrict__ W1,
                                               unsigned short* __restrict__ W1p) {
  int idx = blockIdx.x * 256 + threadIdx.x;  // 8192 total
  int nf = idx >> 9, rem = idx & 511;
  int ks = rem >> 6, lane = rem & 63;
  int n = nf * 16 + (lane & 15);
  int kb = ks * 32 + (lane >> 4) * 8;
#pragma unroll
  for (int j = 0; j < 8; ++j)
    W1p[(size_t)idx * 8 + j] = f2bf(W1[(kb + j) * 256 + n]);
}

// MFMA GEMM: feat_bf16 = bf16(x) @ bf16(W1). Wave: 32 rows x 256 cols.
__global__ __launch_bounds__(256) void k_gemm1m(
    const float* __restrict__ x, const unsigned short* __restrict__ W1p,
    unsigned short* __restrict__ featb, int n) {
  int w = threadIdx.x >> 6, lane = threadIdx.x & 63;
  int tile = (blockIdx.x * 4 + w) * 32;
  if (tile >= n) return;
  int r0 = lane & 15, kgrp = lane >> 4;
  f32x4 acc[16][2];
#pragma unroll
  for (int nf = 0; nf < 16; ++nf)
#pragma unroll
    for (int mf = 0; mf < 2; ++mf) acc[nf][mf] = (f32x4){0.f, 0.f, 0.f, 0.f};

  for (int ks = 0; ks < 8; ++ks) {
    int kb = ks * 32 + kgrp * 8;
    short8 a0, a1;
    {
      int row = tile + r0;
      const float* p = x + (size_t)row * 256 + kb;
      float4 v0 = *reinterpret_cast<const float4*>(p);
      float4 v1 = *reinterpret_cast<const float4*>(p + 4);
      a0[0] = (short)f2bf(v0.x); a0[1] = (short)f2bf(v0.y);
      a0[2] = (short)f2bf(v0.z); a0[3] = (short)f2bf(v0.w);
      a0[4] = (short)f2bf(v1.x); a0[5] = (short)f2bf(v1.y);
      a0[6] = (short)f2bf(v1.z); a0[7] = (short)f2bf(v1.w);
    }
    {
      int row = tile + 16 + r0;
      if (row < n) {
        const float* p = x + (size_t)row * 256 + kb;
        float4 v0 = *reinterpret_cast<const float4*>(p);
        float4 v1 = *reinterpret_cast<const float4*>(p + 4);
        a1[0] = (short)f2bf(v0.x); a1[1] = (short)f2bf(v0.y);
        a1[2] = (short)f2bf(v0.z); a1[3] = (short)f2bf(v0.w);
        a1[4] = (short)f2bf(v1.x); a1[5] = (short)f2bf(v1.y);
        a1[6] = (short)f2bf(v1.z); a1[7] = (short)f2bf(v1.w);
      } else {
#pragma unroll
        for (int j = 0; j < 8; ++j) a1[j] = 0;
      }
    }
#pragma unroll
    for (int nf = 0; nf < 16; ++nf) {
      short8 b = *reinterpret_cast<const short8*>(
          W1p + ((size_t)(nf * 8 + ks) * 64 + lane) * 8);
      acc[nf][0] = __builtin_amdgcn_mfma_f32_16x16x32_bf16(a0, b, acc[nf][0], 0, 0, 0);
      acc[nf][1] = __builtin_amdgcn_mfma_f32_16x16x32_bf16(a1, b, acc[nf][1], 0, 0, 0);
    }
  }
#pragma unroll
  for (int nf = 0; nf < 16; ++nf)
#pragma unroll
    for (int mf = 0; mf < 2; ++mf)
#pragma unroll
      for (int q = 0; q < 4; ++q) {
        int row = tile + mf * 16 + kgrp * 4 + q;
        if (row < n)
          featb[(size_t)row * 256 + nf * 16 + r0] = f2bf(acc[nf][mf][q]);
      }
}

// el/er from bf16 feat. 4 rows/block; 8-lane xor reduce per head.
__global__ __launch_bounds__(256) void k_el(const unsigned short* __restrict__ featb,
                                            const float* __restrict__ al,
                                            const float* __restrict__ ar,
                                            float* __restrict__ el,
                                            float* __restrict__ er, int n) {
  int row = blockIdx.x * 4 + (threadIdx.x >> 6);
  int lane = threadIdx.x & 63;
  if (row >= n) return;
  ushort4 v = *reinterpret_cast<const ushort4*>(featb + (size_t)row * 256 + lane * 4);
  float f0 = bf2f(v.x), f1 = bf2f(v.y), f2 = bf2f(v.z), f3 = bf2f(v.w);
  int c = lane * 4;
  float pl = f0 * al[c] + f1 * al[c + 1] + f2 * al[c + 2] + f3 * al[c + 3];
  float pr = f0 * ar[c] + f1 * ar[c + 1] + f2 * ar[c + 2] + f3 * ar[c + 3];
#pragma unroll
  for (int off = 1; off < 8; off <<= 1) {
    pl += __shfl_xor(pl, off, 64);
    pr += __shfl_xor(pr, off, 64);
  }
  if ((lane & 7) == 0) {
    el[row * 8 + (lane >> 3)] = pl;
    er[row * 8 + (lane >> 3)] = pr;
  }
}

// Wave per dst node. Lane l owns cols l*4..l*4+3 (head hh=l>>3).
// 8-edge groups: lane (e=l>>3, h=l&7) computes ee once; shuffle-broadcast.
__global__ __launch_bounds__(256) void k_agg1(
    const unsigned short* __restrict__ featb, const float* __restrict__ el,
    const float* __restrict__ er, const int* __restrict__ offs,
    const int* __restrict__ csr, const float* __restrict__ b1,
    const float* __restrict__ W2, const float* __restrict__ al2,
    const float* __restrict__ ar2, float4* __restrict__ node4, int n) {
  int dn = blockIdx.x * 4 + (threadIdx.x >> 6);
  if (dn >= n) return;
  int l = threadIdx.x & 63;
  int hh = l >> 3;  // head of this lane's 4 output cols
  int h8 = l & 7;   // head for ee computation
  float erv = er[dn * 8 + h8];
  int beg = offs[dn], end = offs[dn + 1];
  float4 acc = {0.f, 0.f, 0.f, 0.f};
  float den = 0.f;
  int g = beg;
  for (; g + 8 <= end; g += 8) {
    int s_my = csr[g + (l >> 3)];
    float eev = lrelu_exp(el[s_my * 8 + h8] + erv);
#pragma unroll
    for (int e = 0; e < 8; ++e) {
      int s = __shfl(s_my, e * 8, 64);
      float ee = __shfl(eev, e * 8 + hh, 64);
      den += ee;
      ushort4 fv = *reinterpret_cast<const ushort4*>(featb + (size_t)s * 256 + l * 4);
      acc.x = fmaf(ee, bf2f(fv.x), acc.x);
      acc.y = fmaf(ee, bf2f(fv.y), acc.y);
      acc.z = fmaf(ee, bf2f(fv.z), acc.z);
      acc.w = fmaf(ee, bf2f(fv.w), acc.w);
    }
  }
  if (g < end) {
    int rem = end - g;
    int idx = g + (l >> 3);
    int s_my = csr[idx < end ? idx : end - 1];
    float eev = lrelu_exp(el[s_my * 8 + h8] + erv);
    for (int e = 0; e < rem; ++e) {
      int s = __shfl(s_my, e * 8, 64);
      float ee = __shfl(eev, e * 8 + hh, 64);
      den += ee;
      ushort4 fv = *reinterpret_cast<const ushort4*>(featb + (size_t)s * 256 + l * 4);
      acc.x = fmaf(ee, bf2f(fv.x), acc.x);
      acc.y = fmaf(ee, bf2f(fv.y), acc.y);
      acc.z = fmaf(ee, bf2f(fv.z), acc.z);
      acc.w = fmaf(ee, bf2f(fv.w), acc.w);
    }
  }
  float4 bv = *reinterpret_cast<const float4*>(b1 + l * 4);
  float4 w2e = *reinterpret_cast<const float4*>(W2 + l * 8);
  float4 w2o = *reinterpret_cast<const float4*>(W2 + l * 8 + 4);
  float inv = 1.f / fmaxf(den, 1e-16f);
  float v0 = acc.x * inv + bv.x; v0 = v0 > 0.f ? v0 : expm1f(v0);
  float v1 = acc.y * inv + bv.y; v1 = v1 > 0.f ? v1 : expm1f(v1);
  float v2 = acc.z * inv + bv.z; v2 = v2 > 0.f ? v2 : expm1f(v2);
  float v3 = acc.w * inv + bv.w; v3 = v3 > 0.f ? v3 : expm1f(v3);
  float p0 = v0 * w2e.x + v1 * w2e.z + v2 * w2o.x + v3 * w2o.z;
  float p1 = v0 * w2e.y + v1 * w2e.w + v2 * w2o.y + v3 * w2o.w;
#pragma unroll
  for (int off = 32; off; off >>= 1) {
    p0 += __shfl_xor(p0, off, 64);
    p1 += __shfl_xor(p1, off, 64);
  }
  if (l == 0) {
    float e2 = p0 * al2[0] + p1 * al2[1];
    float r2 = p0 * ar2[0] + p1 * ar2[1];
    node4[dn] = make_float4(p0, p1, e2, r2);
  }
}

// Wave per dst node; single float4 gather per edge; fused log_softmax.
__global__ __launch_bounds__(256) void k_agg2(
    const float4* __restrict__ node4, const int* __restrict__ offs,
    const int* __restrict__ csr, const float* __restrict__ b2,
    float* __restrict__ out, int n) {
  int dn = blockIdx.x * 4 + (threadIdx.x >> 6);
  int l = threadIdx.x & 63;
  if (dn >= n) return;
  float erd = node4[dn].w;
  int beg = offs[dn], end = offs[dn + 1];
  float den = 0.f, a0 = 0.f, a1 = 0.f;
  for (int e = beg + l; e < end; e += 64) {
    int s = csr[e];
    float4 n4 = node4[s];
    float ev = n4.z + erd;
    ev = ev >= 0.f ? ev : 0.2f * ev;
    float ee = __expf(ev);
    den += ee;
    a0 = fmaf(ee, n4.x, a0);
    a1 = fmaf(ee, n4.y, a1);
  }
#pragma unroll
  for (int off = 32; off; off >>= 1) {
    den += __shfl_xor(den, off, 64);
    a0 += __shfl_xor(a0, off, 64);
    a1 += __shfl_xor(a1, off, 64);
  }
  if (l == 0) {
    float inv = 1.f / fmaxf(den, 1e-16f);
    float z0 = a0 * inv + b2[0];
    float z1 = a1 * inv + b2[1];
    float m = fmaxf(z0, z1);
    float lse = m + logf(__expf(z0 - m) + __expf(z1 - m));
    out[dn * 2 + 0] = z0 - lse;
    out[dn * 2 + 1] = z1 - lse;
  }
}

extern "C" void kernel_launch(void* const* d_in, const int* in_sizes, int n_in,
                              void* d_out, int out_size, void* d_ws,
                              size_t ws_size, hipStream_t stream) {
  const float* x   = (const float*)d_in[0];
  const int* esrc  = (const int*)d_in[1];
  const int* edst  = (const int*)d_in[2];
  const float* W1  = (const float*)d_in[3];
  const float* al1 = (const float*)d_in[4];
  const float* ar1 = (const float*)d_in[5];
  const float* b1  = (const float*)d_in[6];
  const float* W2  = (const float*)d_in[7];
  const float* al2 = (const float*)d_in[8];
  const float* ar2 = (const float*)d_in[9];
  const float* b2  = (const float*)d_in[10];
  float* out = (float*)d_out;

  size_t off = 0;
  auto alloc = [&](size_t bytes) {
    void* p = (char*)d_ws + off;
    off += (bytes + 255) & ~(size_t)255;
    return p;
  };
  unsigned short* featb = (unsigned short*)alloc((size_t)NN * 256 * 2);
  unsigned short* W1p   = (unsigned short*)alloc((size_t)16 * 8 * 64 * 8 * 2);
  float* el1    = (float*)alloc((size_t)NN * 8 * 4);
  float* er1    = (float*)alloc((size_t)NN * 8 * 4);
  float4* node4 = (float4*)alloc((size_t)NN * 16);
  int2* stage   = (int2*)alloc((size_t)NE * 8);
  int* csr      = (int*)alloc((size_t)NE * 4);
  int* offs     = (int*)alloc((size_t)(NN + 1) * 4);
  int* bcnt     = (int*)alloc((size_t)NBK * 4);
  int* bbase    = (int*)alloc((size_t)(NBK + 1) * 4);
  int* bcursor  = (int*)alloc((size_t)NBK * 4);

  hipMemsetAsync(bcnt, 0, (size_t)NBK * 4, stream);
  k_bcount<<<256, 256, 0, stream>>>(edst, bcnt, NE);
  k_bscan<<<1, 256, 0, stream>>>(bcnt, bbase, bcursor);
  k_part<<<256, 256, 0, stream>>>(edst, esrc, bcursor, stage, NE);
  k_build<<<NBK, 256, 0, stream>>>(stage, bbase, offs, csr, NN, NE);

  k_packw<<<32, 256, 0, stream>>>(W1, W1p);
  k_gemm1m<<<(NN / 32 + 4) / 4, 256, 0, stream>>>(x, W1p, featb, NN);
  k_el<<<(NN + 3) / 4, 256, 0, stream>>>(featb, al1, ar1, el1, er1, NN);
  k_agg1<<<(NN + 3) / 4, 256, 0, stream>>>(featb, el1, er1, offs, csr, b1, W2,
                                           al2, ar2, node4, NN);
  k_agg2<<<(NN + 3) / 4, 256, 0, stream>>>(node4, offs, csr, b2, out, NN);
}